// Round 7
// baseline (329.597 us; speedup 1.0000x reference)
//
#include <hip/hip_runtime.h>
#include <math.h>

#define P_TOT 100000
#define BM    16
#define NBLK  6250

// ws float offsets
#define OFF_BIH   0        // 49152 f32-slots: 192 frag-blocks (6kc x 2hl x 16nt) x 1KB bf16
#define OFF_BHH   49152    // 16384: 64 frag-blocks (2kc x 2hl x 16nt)
#define OFF_BA    65536    // 8192:  32 frag-blocks (2kc x 2hl x 8nt)
#define OFF_BSUM  73728    // 256  (b_ih+b_hh, natural order)
#define OFF_CTXP  73984    // 128  (ctx part of att hidden preact)
#define OFF_MISC  74112    // [0]=safety, [1]=invZ
#define OFF_E     74128    // 100000 exp(score)
#define OFF_PE    174128   // 6250 partial sum e
#define OFF_PAGG  180384   // 6250*64 partial sum e*h
#define OFF_P2E   580384   // 64 stage-2 partial sum e
#define OFF_P2AGG 580448   // 256*64 stage-2 partial sum e*h
// bf16 hi/lo embedding tables: [row][128B hi | 128B lo] = 64 f32-slots/row
#define OFF_TAB   596864
#define OFF_TU    (OFF_TAB)                 // user:   100000 rows
#define OFF_TI    (OFF_TAB + 6400000)       // item:    50000 rows
#define OFF_TR    (OFF_TAB + 9600000)       // rel:         8 rows
#define OFF_TT    (OFF_TAB + 9600512)       // type:        2 rows
#define WS_FAST_BYTES ((size_t)(OFF_TAB + 9600640) * 4)

// klstm LDS layout (38976 B):
//  AF_HI @0     (6144): one-step A hi  [16p][384B], swizzled
//  AF_LO @6144  (6144): one-step A lo
//  ZBUF  @12288 (16384): Z[16p][256n] f32   (HIDB 16x128 f32 overlays after step 3)
//  AH_HI @28672 (2048): h bf16 hi [16p][128B], swizzled
//  AH_LO @30720 (2048)
//  HBUF  @32768 (4096): h_n f32 [16p][64d]
//  ES    @36864 (64)
//  PART  @36928 (2048)
#define AF_HI 0
#define AF_LO 6144
#define ZB    12288
#define AHH   28672
#define AHL   30720
#define HB    32768
#define ESO   36864
#define PARTO 36928
#define LDS_BYTES 38976

typedef short bf16x8 __attribute__((ext_vector_type(8)));
typedef float f32x4  __attribute__((ext_vector_type(4)));

#define MFMA16(a,b,c) __builtin_amdgcn_mfma_f32_16x16x32_bf16((a),(b),(c),0,0,0)

__device__ __forceinline__ void cvthl(float v, unsigned short& h, unsigned short& l){
  unsigned int u  = __float_as_uint(v);
  unsigned int hr = (u + 0x7fffu + ((u>>16)&1u)) >> 16;
  float hf = __uint_as_float(hr<<16);
  unsigned int u2 = __float_as_uint(v - hf);
  unsigned int lr = (u2 + 0x7fffu + ((u2>>16)&1u)) >> 16;
  h = (unsigned short)hr; l = (unsigned short)lr;
}
__device__ __forceinline__ float sigm_f(float x){ return 1.f/(1.f+__expf(-x)); }
__device__ __forceinline__ float tanh_f(float x){
  float e2 = __expf(2.f*x);
  return (e2-1.f)/(e2+1.f);
}

// ---------------------------------------------------------------- prep (weights)
__global__ __launch_bounds__(256) void kprep(
    const int* __restrict__ user_idx, const int* __restrict__ item_idx,
    const float* __restrict__ user_emb, const float* __restrict__ item_emb,
    const float* __restrict__ W_ih, const float* __restrict__ W_hh,
    const float* __restrict__ b_ih, const float* __restrict__ b_hh,
    const float* __restrict__ att_W1, const float* __restrict__ att_b1,
    const float* __restrict__ saf_W1, const float* __restrict__ saf_b1,
    const float* __restrict__ saf_W2, const float* __restrict__ saf_b2,
    float* __restrict__ ws)
{
  const int t = threadIdx.x;
  for (int fb = blockIdx.x; fb < 288; fb += gridDim.x){
    const float* src; int base, rowlen, kc, hl, ntg;
    if (fb < 192){ kc = fb>>5; int rem = fb&31; hl = rem>>4; ntg = rem&15;
                   base = OFF_BIH + fb*256; src = W_ih; rowlen = 192; }
    else if (fb < 256){ int f2 = fb-192; kc = f2>>5; int rem = f2&31; hl = rem>>4; ntg = rem&15;
                   base = OFF_BHH + f2*256; src = W_hh; rowlen = 64; }
    else { int f3 = fb-256; kc = f3>>4; int rem = f3&15; hl = rem>>3; ntg = rem&7;
                   base = OFF_BA + f3*256; src = att_W1; rowlen = 192; }
    unsigned short* dst = (unsigned short*)(ws + base);
    for (int e = t; e < 512; e += 256){
      int l = e>>3, j = e&7;
      int n = ntg*16 + (l&15);
      int k = kc*32 + (l>>4)*8 + j;
      float v = src[n*rowlen + k];
      unsigned short h, lo; cvthl(v, h, lo);
      dst[e] = hl ? lo : h;
    }
  }
  if (blockIdx.x == 0){
    __shared__ float ctx[128];
    if (t < 256) ws[OFF_BSUM+t] = b_ih[t] + b_hh[t];
    if (t < 64){
      ctx[t]    = user_emb[user_idx[0]*64 + t];
      ctx[64+t] = item_emb[item_idx[0]*64 + t];
    }
    __syncthreads();
    if (t < 128){
      float s = att_b1[t];
      for (int k=0;k<128;++k) s = fmaf(att_W1[t*192 + 64 + k], ctx[k], s);
      ws[OFF_CTXP + t] = s;
    }
    if (t < 32){
      float s = saf_b1[t];
      for (int k=0;k<128;++k) s = fmaf(saf_W1[t*128+k], ctx[k], s);
      s = fmaxf(s, 0.f);
      float v = s * saf_W2[t];
      v += __shfl_xor(v,1); v += __shfl_xor(v,2); v += __shfl_xor(v,4);
      v += __shfl_xor(v,8); v += __shfl_xor(v,16);
      if (t==0) ws[OFF_MISC+0] = 1.f/(1.f+expf(-(v + saf_b2[0])));
    }
  }
}

// ---------------------------------------------------------------- table conversion (fast path)
__global__ __launch_bounds__(256) void kconv(
    const float* __restrict__ user_emb, const float* __restrict__ item_emb,
    const float* __restrict__ relation_emb, const float* __restrict__ node_type_emb,
    float* __restrict__ ws)
{
  const int gid = blockIdx.x*256 + threadIdx.x;
  const int row = gid >> 3, seg = gid & 7;
  if (row >= 150010) return;
  const float* src; int dstoff;
  if (row < 100000){ src = user_emb + row*64;             dstoff = OFF_TU + row*64; }
  else if (row < 150000){ src = item_emb + (row-100000)*64; dstoff = OFF_TI + (row-100000)*64; }
  else if (row < 150008){ src = relation_emb + (row-150000)*64; dstoff = OFF_TR + (row-150000)*64; }
  else { src = node_type_emb + (row-150008)*64;           dstoff = OFF_TT + (row-150008)*64; }
  float4 v0 = ((const float4*)(src + seg*8))[0];
  float4 v1 = ((const float4*)(src + seg*8))[1];
  float vv[8] = {v0.x,v0.y,v0.z,v0.w,v1.x,v1.y,v1.z,v1.w};
  unsigned short h[8], lo[8];
  #pragma unroll
  for (int j=0;j<8;++j) cvthl(vv[j], h[j], lo[j]);
  uint4 hq, lq;
  hq.x = (unsigned)h[0] | ((unsigned)h[1]<<16);  hq.y = (unsigned)h[2] | ((unsigned)h[3]<<16);
  hq.z = (unsigned)h[4] | ((unsigned)h[5]<<16);  hq.w = (unsigned)h[6] | ((unsigned)h[7]<<16);
  lq.x = (unsigned)lo[0]| ((unsigned)lo[1]<<16); lq.y = (unsigned)lo[2]| ((unsigned)lo[3]<<16);
  lq.z = (unsigned)lo[4]| ((unsigned)lo[5]<<16); lq.w = (unsigned)lo[6]| ((unsigned)lo[7]<<16);
  char* dst = (char*)(ws + dstoff);
  *(uint4*)(dst + seg*16)       = hq;
  *(uint4*)(dst + 128 + seg*16) = lq;
}

// ---------------------------------------------------------------- main: LSTM + attention
// per-step interleaved: acc[2] (8 AGPR); gather(s+1) hidden under gates(s)
template<int PRE>
__global__ __launch_bounds__(512,6) void klstm(
    const int* __restrict__ node_ids, const int* __restrict__ node_types,
    const int* __restrict__ rel_idx,
    const float* __restrict__ user_emb, const float* __restrict__ item_emb,
    const float* __restrict__ relation_emb, const float* __restrict__ node_type_emb,
    const float* __restrict__ att_W2, const float* __restrict__ att_b2,
    float* __restrict__ ws)
{
  __shared__ __align__(16) unsigned char smem[LDS_BYTES];
  const int t   = threadIdx.x;
  const int l   = t & 63, wid = t >> 6;
  const int ln  = l & 15, lk = l >> 4;
  const int bid = blockIdx.x, p0 = bid*BM;
  const int n0  = wid*32;
  const bf16x8* Bih = (const bf16x8*)(ws + OFF_BIH);
  const bf16x8* Bhh = (const bf16x8*)(ws + OFF_BHH);
  const bf16x8* Bab = (const bf16x8*)(ws + OFF_BA);
  const int swA = (ln&7)<<4;

  // gather thread mapping (t<384): rr=t>>3 -> src=rr>>4, p=rr&15; c8=t&7
  const int g_c8 = t&7, g_src = (t>>3)>>4, g_p = (t>>3)&15;
  const int g_sw = (g_p&7)<<4;
  const int g_kb = (g_src*128 + g_c8*16) ^ g_sw;

  const float b0 = ws[OFF_BSUM + n0 + ln];
  const float b1 = ws[OFF_BSUM + n0 + 16 + ln];

  // ---- prologue: gather step 0
  if (t < 384){
    int gi = (p0+g_p)*4 + 0;
    if (PRE){
      const char* rp;
      if (g_src==0){ int nid = node_ids[gi];
                     rp = (const char*)(ws + (node_types[gi]==0 ? OFF_TU + nid*64 : OFF_TI + nid*64)); }
      else if (g_src==1){ rp = (const char*)(ws + OFF_TT + node_types[gi]*64); }
      else { rp = (const char*)(ws + OFF_TR + rel_idx[gi]*64); }
      *(uint4*)(smem + AF_HI + g_p*384 + g_kb) = *(const uint4*)(rp + g_c8*16);
      *(uint4*)(smem + AF_LO + g_p*384 + g_kb) = *(const uint4*)(rp + 128 + g_c8*16);
    } else {
      const float* sp;
      if (g_src==0){ int nid = node_ids[gi]; sp = (node_types[gi]==0 ? user_emb : item_emb) + nid*64; }
      else if (g_src==1){ sp = node_type_emb + node_types[gi]*64; }
      else { sp = relation_emb + rel_idx[gi]*64; }
      float4 v0 = ((const float4*)sp)[g_c8*2];
      float4 v1 = ((const float4*)sp)[g_c8*2+1];
      float vv[8] = {v0.x,v0.y,v0.z,v0.w,v1.x,v1.y,v1.z,v1.w};
      unsigned short h[8], lo[8];
      #pragma unroll
      for (int j=0;j<8;++j) cvthl(vv[j], h[j], lo[j]);
      uint4 hq, lq;
      hq.x=(unsigned)h[0]|((unsigned)h[1]<<16);  hq.y=(unsigned)h[2]|((unsigned)h[3]<<16);
      hq.z=(unsigned)h[4]|((unsigned)h[5]<<16);  hq.w=(unsigned)h[6]|((unsigned)h[7]<<16);
      lq.x=(unsigned)lo[0]|((unsigned)lo[1]<<16); lq.y=(unsigned)lo[2]|((unsigned)lo[3]<<16);
      lq.z=(unsigned)lo[4]|((unsigned)lo[5]<<16); lq.w=(unsigned)lo[6]|((unsigned)lo[7]<<16);
      *(uint4*)(smem + AF_HI + g_p*384 + g_kb) = hq;
      *(uint4*)(smem + AF_LO + g_p*384 + g_kb) = lq;
    }
  }
  __syncthreads();

  const int gp = t>>5, gd = (t&31)*2;     // gate thread -> (path, 2 dims)
  const int swg = (gp&7)<<4;
  float c0 = 0.f, c1 = 0.f;

  #pragma unroll
  for (int s=0; s<4; ++s){
    // ---- phase 1: Z = bias + x_s@Wih (+ h@Whh for s>0)
    f32x4 acc0 = (f32x4){b0,b0,b0,b0};
    f32x4 acc1 = (f32x4){b1,b1,b1,b1};
    #pragma unroll 2
    for (int kc=0;kc<6;++kc){
      bf16x8 bh0 = Bih[(unsigned)(((kc*2+0)*16 + wid*2+0)*64 + l)];
      bf16x8 bh1 = Bih[(unsigned)(((kc*2+0)*16 + wid*2+1)*64 + l)];
      bf16x8 bl0 = Bih[(unsigned)(((kc*2+1)*16 + wid*2+0)*64 + l)];
      bf16x8 bl1 = Bih[(unsigned)(((kc*2+1)*16 + wid*2+1)*64 + l)];
      bf16x8 ah = *(const bf16x8*)(smem + AF_HI + ln*384 + ((kc*64 + lk*16) ^ swA));
      bf16x8 al = *(const bf16x8*)(smem + AF_LO + ln*384 + ((kc*64 + lk*16) ^ swA));
      acc0 = MFMA16(ah, bh0, acc0);
      acc0 = MFMA16(al, bh0, acc0);
      acc0 = MFMA16(ah, bl0, acc0);
      acc1 = MFMA16(ah, bh1, acc1);
      acc1 = MFMA16(al, bh1, acc1);
      acc1 = MFMA16(ah, bl1, acc1);
    }
    if (s > 0){
      #pragma unroll
      for (int kc=0;kc<2;++kc){
        bf16x8 ah = *(const bf16x8*)(smem + AHH + ln*128 + ((kc*64 + lk*16) ^ swA));
        bf16x8 al = *(const bf16x8*)(smem + AHL + ln*128 + ((kc*64 + lk*16) ^ swA));
        bf16x8 bh0 = Bhh[(unsigned)(((kc*2+0)*16 + wid*2+0)*64 + l)];
        bf16x8 bh1 = Bhh[(unsigned)(((kc*2+0)*16 + wid*2+1)*64 + l)];
        bf16x8 bl0 = Bhh[(unsigned)(((kc*2+1)*16 + wid*2+0)*64 + l)];
        bf16x8 bl1 = Bhh[(unsigned)(((kc*2+1)*16 + wid*2+1)*64 + l)];
        acc0 = MFMA16(ah, bh0, acc0);
        acc0 = MFMA16(al, bh0, acc0);
        acc0 = MFMA16(ah, bl0, acc0);
        acc1 = MFMA16(ah, bh1, acc1);
        acc1 = MFMA16(al, bh1, acc1);
        acc1 = MFMA16(ah, bl1, acc1);
      }
    }
    // write Z tile (C layout: row=lk*4+r, col=ln)
    #pragma unroll
    for (int r=0;r<4;++r){
      *(float*)(smem + ZB + (lk*4+r)*1024 + (n0 + ln)*4)      = acc0[r];
      *(float*)(smem + ZB + (lk*4+r)*1024 + (n0 + 16 + ln)*4) = acc1[r];
    }
    __syncthreads();

    // ---- gather loads for step s+1 (issued early, consumed after gates)
    uint4 hq, lq;
    float4 gv0, gv1;
    const bool gact = (s < 3) && (t < 384);
    if (gact){
      int gi = (p0+g_p)*4 + s + 1;
      if (PRE){
        const char* rp;
        if (g_src==0){ int nid = node_ids[gi];
                       rp = (const char*)(ws + (node_types[gi]==0 ? OFF_TU + nid*64 : OFF_TI + nid*64)); }
        else if (g_src==1){ rp = (const char*)(ws + OFF_TT + node_types[gi]*64); }
        else { rp = (const char*)(ws + OFF_TR + rel_idx[gi]*64); }
        hq = *(const uint4*)(rp + g_c8*16);
        lq = *(const uint4*)(rp + 128 + g_c8*16);
      } else {
        const float* sp;
        if (g_src==0){ int nid = node_ids[gi]; sp = (node_types[gi]==0 ? user_emb : item_emb) + nid*64; }
        else if (g_src==1){ sp = node_type_emb + node_types[gi]*64; }
        else { sp = relation_emb + rel_idx[gi]*64; }
        gv0 = ((const float4*)sp)[g_c8*2];
        gv1 = ((const float4*)sp)[g_c8*2+1];
      }
    }

    // ---- gates
    {
      float2 zi = *(float2*)(smem + ZB + gp*1024 +        gd*4);
      float2 zf = *(float2*)(smem + ZB + gp*1024 + 256  + gd*4);
      float2 zg = *(float2*)(smem + ZB + gp*1024 + 512  + gd*4);
      float2 zo = *(float2*)(smem + ZB + gp*1024 + 768  + gd*4);
      float i0 = sigm_f(zi.x), i1 = sigm_f(zi.y);
      float f0 = sigm_f(zf.x), f1 = sigm_f(zf.y);
      float g0 = tanh_f(zg.x), g1 = tanh_f(zg.y);
      float o0 = sigm_f(zo.x), o1 = sigm_f(zo.y);
      c0 = fmaf(f0, c0, i0*g0);
      c1 = fmaf(f1, c1, i1*g1);
      float h0 = o0 * tanh_f(c0);
      float h1 = o1 * tanh_f(c1);
      if (s == 3) *(float2*)(smem + HB + gp*256 + gd*4) = make_float2(h0, h1);
      unsigned short hh0,ll0,hh1,ll1;
      cvthl(h0, hh0, ll0); cvthl(h1, hh1, ll1);
      *(unsigned*)(smem + AHH + gp*128 + ((gd*2) ^ swg)) = (unsigned)hh0 | ((unsigned)hh1<<16);
      *(unsigned*)(smem + AHL + gp*128 + ((gd*2) ^ swg)) = (unsigned)ll0 | ((unsigned)ll1<<16);
    }

    // ---- gather writes (A tile for step s+1)
    if (gact){
      if (!PRE){
        float vv[8] = {gv0.x,gv0.y,gv0.z,gv0.w,gv1.x,gv1.y,gv1.z,gv1.w};
        unsigned short h[8], lo[8];
        #pragma unroll
        for (int j=0;j<8;++j) cvthl(vv[j], h[j], lo[j]);
        hq.x=(unsigned)h[0]|((unsigned)h[1]<<16);  hq.y=(unsigned)h[2]|((unsigned)h[3]<<16);
        hq.z=(unsigned)h[4]|((unsigned)h[5]<<16);  hq.w=(unsigned)h[6]|((unsigned)h[7]<<16);
        lq.x=(unsigned)lo[0]|((unsigned)lo[1]<<16); lq.y=(unsigned)lo[2]|((unsigned)lo[3]<<16);
        lq.z=(unsigned)lo[4]|((unsigned)lo[5]<<16); lq.w=(unsigned)lo[6]|((unsigned)lo[7]<<16);
      }
      *(uint4*)(smem + AF_HI + g_p*384 + g_kb) = hq;
      *(uint4*)(smem + AF_LO + g_p*384 + g_kb) = lq;
    }
    __syncthreads();
  }

  // ---- attention hidden: relu(h @ BA + ctxp) -> HIDB (overlay ZBUF)
  if (wid < 4){
    f32x4 acc2[2];
    #pragma unroll
    for (int nt=0;nt<2;++nt){
      float cv = ws[OFF_CTXP + wid*32 + nt*16 + ln];
      acc2[nt] = (f32x4){cv,cv,cv,cv};
    }
    #pragma unroll
    for (int kc=0;kc<2;++kc){
      bf16x8 ah = *(const bf16x8*)(smem + AHH + ln*128 + ((kc*64 + lk*16) ^ swA));
      bf16x8 al = *(const bf16x8*)(smem + AHL + ln*128 + ((kc*64 + lk*16) ^ swA));
      bf16x8 bh0 = Bab[(unsigned)(((kc*2+0)*8 + wid*2+0)*64 + l)];
      bf16x8 bh1 = Bab[(unsigned)(((kc*2+0)*8 + wid*2+1)*64 + l)];
      bf16x8 bl0 = Bab[(unsigned)(((kc*2+1)*8 + wid*2+0)*64 + l)];
      bf16x8 bl1 = Bab[(unsigned)(((kc*2+1)*8 + wid*2+1)*64 + l)];
      acc2[0] = MFMA16(ah, bh0, acc2[0]);
      acc2[0] = MFMA16(al, bh0, acc2[0]);
      acc2[0] = MFMA16(ah, bl0, acc2[0]);
      acc2[1] = MFMA16(ah, bh1, acc2[1]);
      acc2[1] = MFMA16(al, bh1, acc2[1]);
      acc2[1] = MFMA16(ah, bl1, acc2[1]);
    }
    #pragma unroll
    for (int nt=0;nt<2;++nt)
      #pragma unroll
      for (int r=0;r<4;++r)
        *(float*)(smem + ZB + (lk*4+r)*512 + (wid*32 + nt*16 + ln)*4) = fmaxf(acc2[nt][r], 0.f);
  }
  __syncthreads();
  // ---- score = hidden . att_W2 + b2 ; e = exp(score)
  {
    int sp2 = t>>5, seg = t&31;
    float4 a = *(const float4*)(smem + ZB + sp2*512 + seg*16);
    float4 w = *(const float4*)(att_W2 + seg*4);
    float sc = a.x*w.x; sc = fmaf(a.y,w.y,sc); sc = fmaf(a.z,w.z,sc); sc = fmaf(a.w,w.w,sc);
    sc += __shfl_xor(sc,1); sc += __shfl_xor(sc,2); sc += __shfl_xor(sc,4);
    sc += __shfl_xor(sc,8); sc += __shfl_xor(sc,16);
    if (seg == 0){
      float e = __expf(sc + att_b2[0]);
      *(float*)(smem + ESO + sp2*4) = e;
      ws[OFF_E + p0 + sp2] = e;
    }
  }
  __syncthreads();
  // ---- partial sums: sum(e), sum(e*h)
  {
    int pg = t>>6, d = t&63;
    const float* es = (const float*)(smem + ESO);
    float a = es[pg*2]   * (*(const float*)(smem + HB + (pg*2  )*256 + d*4))
            + es[pg*2+1] * (*(const float*)(smem + HB + (pg*2+1)*256 + d*4));
    *(float*)(smem + PARTO + (pg*64+d)*4) = a;
  }
  __syncthreads();
  if (t < 64){
    const float* part = (const float*)(smem + PARTO);
    float a = 0.f;
    #pragma unroll
    for (int pg=0;pg<8;++pg) a += part[pg*64 + t];
    ws[OFF_PAGG + bid*64 + t] = a;
  }
  if (t < 16){
    float e2 = *(const float*)(smem + ESO + t*4);
    e2 += __shfl_xor(e2,1); e2 += __shfl_xor(e2,2);
    e2 += __shfl_xor(e2,4); e2 += __shfl_xor(e2,8);
    if (t==0) ws[OFF_PE + bid] = e2;
  }
}

// ---------------------------------------------------------------- reduce stage A: 64 blocks
__global__ __launch_bounds__(256) void kredA(float* __restrict__ ws)
{
  const float* p_e   = ws + OFF_PE;
  const float* p_agg = ws + OFF_PAGG;
  __shared__ float red[256];
  const int b = blockIdx.x, t = threadIdx.x;
  const int s = b*4 + (t>>6), d = t&63;
  float a = 0.f;
  for (int row = s; row < NBLK; row += 256) a += p_agg[row*64 + d];
  ws[OFF_P2AGG + s*64 + d] = a;
  float pe = 0.f;
  {
    int i = b*98 + t;
    if (t < 98 && i < NBLK) pe = p_e[i];
  }
  pe += __shfl_xor(pe,1); pe += __shfl_xor(pe,2); pe += __shfl_xor(pe,4);
  pe += __shfl_xor(pe,8); pe += __shfl_xor(pe,16); pe += __shfl_xor(pe,32);
  if ((t&63)==0) red[t>>6] = pe;
  __syncthreads();
  if (t==0) ws[OFF_P2E + b] = red[0]+red[1]+red[2]+red[3];
}

// ---------------------------------------------------------------- reduce stage B + heads: 1 block
__global__ __launch_bounds__(256) void kredB(
    const float* __restrict__ val_W1, const float* __restrict__ val_b1,
    const float* __restrict__ val_W2, const float* __restrict__ val_b2,
    float* __restrict__ ws, float* __restrict__ d_out)
{
  __shared__ float aggL[64];
  __shared__ float red[256];
  __shared__ float Zs;
  const int t = threadIdx.x;
  {
    float pe = (t < 64) ? ws[OFF_P2E + t] : 0.f;
    pe += __shfl_xor(pe,1); pe += __shfl_xor(pe,2); pe += __shfl_xor(pe,4);
    pe += __shfl_xor(pe,8); pe += __shfl_xor(pe,16); pe += __shfl_xor(pe,32);
    if (t==0){ Zs = pe; ws[OFF_MISC+1] = 1.f/pe; }
  }
  {
    int d = t&63, q = t>>6;
    float a = 0.f;
    #pragma unroll 4
    for (int s2=q; s2<256; s2+=4) a += ws[OFF_P2AGG + s2*64 + d];
    red[t] = a;
  }
  __syncthreads();
  if (t < 64) aggL[t] = (red[t] + red[64+t] + red[128+t] + red[192+t]) / Zs;
  __syncthreads();
  if (t < 32){
    float hv = val_b1[t];
    for (int k=0;k<64;++k) hv = fmaf(aggL[k], val_W1[t*64+k], hv);
    hv = fmaxf(hv, 0.f);
    float v = hv * val_W2[t];
    v += __shfl_xor(v,1); v += __shfl_xor(v,2); v += __shfl_xor(v,4);
    v += __shfl_xor(v,8); v += __shfl_xor(v,16);
    // q_value = value + (advantage - mean(advantage)) == value (advantage is [1])
    if (t==0) d_out[0] = (v + val_b2[0]) * ws[OFF_MISC+0];
  }
}

// ---------------------------------------------------------------- att weights out
__global__ __launch_bounds__(256) void kweights(
    const float* __restrict__ ws, float* __restrict__ d_out)
{
  int p = blockIdx.x*256 + threadIdx.x;
  if (p < P_TOT) d_out[1+p] = ws[OFF_E + p] * ws[OFF_MISC+1];
}

// ---------------------------------------------------------------- launch
extern "C" void kernel_launch(void* const* d_in, const int* in_sizes, int n_in,
                              void* d_out, int out_size, void* d_ws, size_t ws_size,
                              hipStream_t stream) {
  const int*   user_idx   = (const int*)  d_in[0];
  const int*   item_idx   = (const int*)  d_in[1];
  const int*   node_ids   = (const int*)  d_in[2];
  const int*   node_types = (const int*)  d_in[3];
  const int*   rel_idx    = (const int*)  d_in[4];
  const float* user_emb   = (const float*)d_in[5];
  const float* item_emb   = (const float*)d_in[6];
  const float* rel_emb    = (const float*)d_in[7];
  const float* ntype_emb  = (const float*)d_in[8];
  const float* W_ih       = (const float*)d_in[9];
  const float* W_hh       = (const float*)d_in[10];
  const float* b_ih       = (const float*)d_in[11];
  const float* b_hh       = (const float*)d_in[12];
  const float* att_W1     = (const float*)d_in[13];
  const float* att_b1     = (const float*)d_in[14];
  const float* att_W2     = (const float*)d_in[15];
  const float* att_b2     = (const float*)d_in[16];
  const float* val_W1     = (const float*)d_in[17];
  const float* val_b1     = (const float*)d_in[18];
  const float* val_W2     = (const float*)d_in[19];
  const float* val_b2     = (const float*)d_in[20];
  const float* saf_W1     = (const float*)d_in[25];
  const float* saf_b1     = (const float*)d_in[26];
  const float* saf_W2     = (const float*)d_in[27];
  const float* saf_b2     = (const float*)d_in[28];
  float* ws  = (float*)d_ws;
  float* out = (float*)d_out;

  const bool fast = (ws_size >= WS_FAST_BYTES);

  hipLaunchKernelGGL(kprep, dim3(64), dim3(256), 0, stream,
                     user_idx, item_idx, user_emb, item_emb,
                     W_ih, W_hh, b_ih, b_hh, att_W1, att_b1,
                     saf_W1, saf_b1, saf_W2, saf_b2, ws);
  if (fast){
    hipLaunchKernelGGL(kconv, dim3((150010*8+255)/256), dim3(256), 0, stream,
                       user_emb, item_emb, rel_emb, ntype_emb, ws);
    hipLaunchKernelGGL(klstm<1>, dim3(NBLK), dim3(512), 0, stream,
                       node_ids, node_types, rel_idx,
                       user_emb, item_emb, rel_emb, ntype_emb,
                       att_W2, att_b2, ws);
  } else {
    hipLaunchKernelGGL(klstm<0>, dim3(NBLK), dim3(512), 0, stream,
                       node_ids, node_types, rel_idx,
                       user_emb, item_emb, rel_emb, ntype_emb,
                       att_W2, att_b2, ws);
  }
  hipLaunchKernelGGL(kredA, dim3(64), dim3(256), 0, stream, ws);
  hipLaunchKernelGGL(kredB, dim3(1), dim3(256), 0, stream,
                     val_W1, val_b1, val_W2, val_b2, ws, out);
  hipLaunchKernelGGL(kweights, dim3((P_TOT+255)/256), dim3(256), 0, stream,
                     ws, out);
}

// Round 8
// 172.627 us; speedup vs baseline: 1.9093x; 1.9093x over previous
//
#include <hip/hip_runtime.h>
#include <math.h>

#define P_TOT 100000
#define BM    16
#define NBLK  6250

// ws float offsets
#define OFF_BIH   0        // 24576: 96 frag-blocks (6kc x 16nt) x 1KB bf16 (hi only)
#define OFF_BHH   24576    // 16384: 64 frag-blocks (2kc x 2hl x 16nt)
#define OFF_BA    40960    // 4096:  16 frag-blocks (2kc x 8nt) hi only
#define OFF_BSUM  45056    // 256  (b_ih+b_hh)
#define OFF_CTXP  45312    // 128
#define OFF_MISC  45440    // [0]=safety, [1]=invZ
#define OFF_E     45456    // 100000 exp(score)
#define OFF_PE    145456   // 6250
#define OFF_PAGG  151712   // 6250*64
#define OFF_P2E   551712   // 64
#define OFF_P2AGG 551776   // 256*64
// bf16 hi/lo embedding tables: [row][128B hi | 128B lo] = 64 f32-slots/row
#define OFF_TAB   568160
#define OFF_TU    (OFF_TAB)
#define OFF_TI    (OFF_TAB + 6400000)
#define OFF_TR    (OFF_TAB + 9600000)
#define OFF_TT    (OFF_TAB + 9600512)
#define WS_FAST_BYTES ((size_t)(OFF_TAB + 9600640) * 4)

// klstm LDS (26688 B):
//  AF @0 (24576): [4s][16p]x384B hi-only swizzled A tiles (phase1)
//  phase2 overlay: ZB @0 (16384) | AHH @16384 (2048) | AHL @18432 (2048) | HB @20480 (4096)
//  attn HIDB overlays ZB; ES @24576 (64) | PART @24640 (2048)
#define AHH 16384
#define AHL 18432
#define HB  20480
#define ESO 24576
#define PARTO 24640
#define LDS_BYTES 26688

typedef short bf16x8 __attribute__((ext_vector_type(8)));
typedef float f32x4  __attribute__((ext_vector_type(4)));

#define MFMA16(a,b,c) __builtin_amdgcn_mfma_f32_16x16x32_bf16((a),(b),(c),0,0,0)

__device__ __forceinline__ void cvthl(float v, unsigned short& h, unsigned short& l){
  unsigned int u  = __float_as_uint(v);
  unsigned int hr = (u + 0x7fffu + ((u>>16)&1u)) >> 16;
  float hf = __uint_as_float(hr<<16);
  unsigned int u2 = __float_as_uint(v - hf);
  unsigned int lr = (u2 + 0x7fffu + ((u2>>16)&1u)) >> 16;
  h = (unsigned short)hr; l = (unsigned short)lr;
}
__device__ __forceinline__ unsigned short cvh(float v){
  unsigned int u = __float_as_uint(v);
  return (unsigned short)((u + 0x7fffu + ((u>>16)&1u)) >> 16);
}
__device__ __forceinline__ float sigm_f(float x){ return 1.f/(1.f+__expf(-x)); }
__device__ __forceinline__ float tanh_f(float x){
  float e2 = __expf(2.f*x);
  return (e2-1.f)/(e2+1.f);
}

// ---------------------------------------------------------------- prep (weights)
__global__ __launch_bounds__(256) void kprep(
    const int* __restrict__ user_idx, const int* __restrict__ item_idx,
    const float* __restrict__ user_emb, const float* __restrict__ item_emb,
    const float* __restrict__ W_ih, const float* __restrict__ W_hh,
    const float* __restrict__ b_ih, const float* __restrict__ b_hh,
    const float* __restrict__ att_W1, const float* __restrict__ att_b1,
    const float* __restrict__ saf_W1, const float* __restrict__ saf_b1,
    const float* __restrict__ saf_W2, const float* __restrict__ saf_b2,
    float* __restrict__ ws)
{
  const int t = threadIdx.x;
  for (int fb = blockIdx.x; fb < 176; fb += gridDim.x){
    const float* src; int base, rowlen, kc, hl, ntg;
    if (fb < 96){ kc = fb>>4; ntg = fb&15; hl = 0;
                  base = OFF_BIH + fb*256; src = W_ih; rowlen = 192; }
    else if (fb < 160){ int f2 = fb-96; kc = f2>>5; int rem = f2&31; hl = rem>>4; ntg = rem&15;
                  base = OFF_BHH + f2*256; src = W_hh; rowlen = 64; }
    else { int f3 = fb-160; kc = f3>>3; ntg = f3&7; hl = 0;
                  base = OFF_BA + f3*256; src = att_W1; rowlen = 192; }
    unsigned short* dst = (unsigned short*)(ws + base);
    for (int e = t; e < 512; e += 256){
      int l = e>>3, j = e&7;
      int n = ntg*16 + (l&15);
      int k = kc*32 + (l>>4)*8 + j;
      float v = src[n*rowlen + k];
      unsigned short h, lo; cvthl(v, h, lo);
      dst[e] = hl ? lo : h;
    }
  }
  if (blockIdx.x == 0){
    __shared__ float ctx[128];
    if (t < 256) ws[OFF_BSUM+t] = b_ih[t] + b_hh[t];
    if (t < 64){
      ctx[t]    = user_emb[user_idx[0]*64 + t];
      ctx[64+t] = item_emb[item_idx[0]*64 + t];
    }
    __syncthreads();
    if (t < 128){
      float s = att_b1[t];
      for (int k=0;k<128;++k) s = fmaf(att_W1[t*192 + 64 + k], ctx[k], s);
      ws[OFF_CTXP + t] = s;
    }
    if (t < 32){
      float s = saf_b1[t];
      for (int k=0;k<128;++k) s = fmaf(saf_W1[t*128+k], ctx[k], s);
      s = fmaxf(s, 0.f);
      float v = s * saf_W2[t];
      v += __shfl_xor(v,1); v += __shfl_xor(v,2); v += __shfl_xor(v,4);
      v += __shfl_xor(v,8); v += __shfl_xor(v,16);
      if (t==0) ws[OFF_MISC+0] = 1.f/(1.f+expf(-(v + saf_b2[0])));
    }
  }
}

// ---------------------------------------------------------------- table conversion (fast path)
__global__ __launch_bounds__(256) void kconv(
    const float* __restrict__ user_emb, const float* __restrict__ item_emb,
    const float* __restrict__ relation_emb, const float* __restrict__ node_type_emb,
    float* __restrict__ ws)
{
  const int gid = blockIdx.x*256 + threadIdx.x;
  const int row = gid >> 3, seg = gid & 7;
  if (row >= 150010) return;
  const float* src; int dstoff;
  if (row < 100000){ src = user_emb + row*64;             dstoff = OFF_TU + row*64; }
  else if (row < 150000){ src = item_emb + (row-100000)*64; dstoff = OFF_TI + (row-100000)*64; }
  else if (row < 150008){ src = relation_emb + (row-150000)*64; dstoff = OFF_TR + (row-150000)*64; }
  else { src = node_type_emb + (row-150008)*64;           dstoff = OFF_TT + (row-150008)*64; }
  float4 v0 = ((const float4*)(src + seg*8))[0];
  float4 v1 = ((const float4*)(src + seg*8))[1];
  float vv[8] = {v0.x,v0.y,v0.z,v0.w,v1.x,v1.y,v1.z,v1.w};
  unsigned short h[8], lo[8];
  #pragma unroll
  for (int j=0;j<8;++j) cvthl(vv[j], h[j], lo[j]);
  uint4 hq, lq;
  hq.x = (unsigned)h[0] | ((unsigned)h[1]<<16);  hq.y = (unsigned)h[2] | ((unsigned)h[3]<<16);
  hq.z = (unsigned)h[4] | ((unsigned)h[5]<<16);  hq.w = (unsigned)h[6] | ((unsigned)h[7]<<16);
  lq.x = (unsigned)lo[0]| ((unsigned)lo[1]<<16); lq.y = (unsigned)lo[2]| ((unsigned)lo[3]<<16);
  lq.z = (unsigned)lo[4]| ((unsigned)lo[5]<<16); lq.w = (unsigned)lo[6]| ((unsigned)lo[7]<<16);
  char* dst = (char*)(ws + dstoff);
  *(uint4*)(dst + seg*16)       = hq;
  *(uint4*)(dst + 128 + seg*16) = lq;
}

// ---------------------------------------------------------------- main: LSTM + attention
// single-bf16 input GEMM + attn; split-bf16 recurrent path only
template<int PRE>
__global__ __launch_bounds__(512,4) void klstm(
    const int* __restrict__ node_ids, const int* __restrict__ node_types,
    const int* __restrict__ rel_idx,
    const float* __restrict__ user_emb, const float* __restrict__ item_emb,
    const float* __restrict__ relation_emb, const float* __restrict__ node_type_emb,
    const float* __restrict__ att_W2, const float* __restrict__ att_b2,
    float* __restrict__ ws)
{
  __shared__ __align__(16) unsigned char smem[LDS_BYTES];
  const int t   = threadIdx.x;
  const int l   = t & 63, wid = t >> 6;
  const int ln  = l & 15, lk = l >> 4;
  const int bid = blockIdx.x, p0 = bid*BM;
  const int n0  = wid*32;
  const bf16x8* Bih = (const bf16x8*)(ws + OFF_BIH);
  const bf16x8* Bhh = (const bf16x8*)(ws + OFF_BHH);
  const bf16x8* Bab = (const bf16x8*)(ws + OFF_BA);
  const int swA = (ln&7)<<4;

  // ---- gather feats (all 4 steps, hi only) -> swizzled bf16 A tiles
  if (t < 384){
    int r = t>>1, half = t&1;
    int s = r/48, rem = r - s*48, src = rem>>4, p = rem&15;
    int gi = (p0+p)*4 + s;
    const int sw = (p&7)<<4;
    const int row = (s*16 + p)*384;
    if (PRE){
      const char* rp;
      if (src==0){ int nid = node_ids[gi];
                   rp = (const char*)(ws + (node_types[gi]==0 ? OFF_TU + nid*64 : OFF_TI + nid*64)); }
      else if (src==1){ rp = (const char*)(ws + OFF_TT + node_types[gi]*64); }
      else { rp = (const char*)(ws + OFF_TR + rel_idx[gi]*64); }
      #pragma unroll
      for (int ii=0; ii<4; ++ii){
        int i = half*4 + ii;
        uint4 hq = *(const uint4*)(rp + i*16);
        int kb = (src*128 + i*16) ^ sw;
        *(uint4*)(smem + row + kb) = hq;
      }
    } else {
      const float* sp;
      if (src==0){ int nid = node_ids[gi]; sp = (node_types[gi]==0 ? user_emb : item_emb) + nid*64; }
      else if (src==1){ sp = node_type_emb + node_types[gi]*64; }
      else { sp = relation_emb + rel_idx[gi]*64; }
      #pragma unroll
      for (int ii=0; ii<4; ++ii){
        int i = half*4 + ii;
        float4 v0 = ((const float4*)sp)[i*2];
        float4 v1 = ((const float4*)sp)[i*2+1];
        uint4 hq;
        hq.x = (unsigned)cvh(v0.x) | ((unsigned)cvh(v0.y)<<16);
        hq.y = (unsigned)cvh(v0.z) | ((unsigned)cvh(v0.w)<<16);
        hq.z = (unsigned)cvh(v1.x) | ((unsigned)cvh(v1.y)<<16);
        hq.w = (unsigned)cvh(v1.z) | ((unsigned)cvh(v1.w)<<16);
        int kb = (src*128 + i*16) ^ sw;
        *(uint4*)(smem + row + kb) = hq;
      }
    }
  }
  // ---- acc init with bias
  f32x4 acc[4][2];
  #pragma unroll
  for (int s=0;s<4;++s)
    #pragma unroll
    for (int nt=0;nt<2;++nt){
      float bv = ws[OFF_BSUM + n0 + nt*16 + ln];
      acc[s][nt] = (f32x4){bv,bv,bv,bv};
    }
  __syncthreads();

  // ---- phase 1: Zfeat for all 4 steps (K=192, single bf16)
  #pragma unroll 2
  for (int kc=0;kc<6;++kc){
    bf16x8 bh0 = Bih[(unsigned)((kc*16 + wid*2+0)*64 + l)];
    bf16x8 bh1 = Bih[(unsigned)((kc*16 + wid*2+1)*64 + l)];
    #pragma unroll
    for (int s=0;s<4;++s){
      bf16x8 ah = *(const bf16x8*)(smem + (s*16+ln)*384 + ((kc*64 + lk*16) ^ swA));
      acc[s][0] = MFMA16(ah, bh0, acc[s][0]);
      acc[s][1] = MFMA16(ah, bh1, acc[s][1]);
    }
  }
  __syncthreads();   // AF dead; overlay live

  // ---- phase 2: recurrence (split bf16 on h and W_hh)
  const int gp = t>>5, gd = (t&31)*2;
  const int swg = (gp&7)<<4;
  float c0 = 0.f, c1 = 0.f;
  #pragma unroll
  for (int s=0;s<4;++s){
    if (s > 0){
      #pragma unroll
      for (int kc=0;kc<2;++kc){
        bf16x8 ah = *(const bf16x8*)(smem + AHH + ln*128 + ((kc*64 + lk*16) ^ swA));
        bf16x8 al = *(const bf16x8*)(smem + AHL + ln*128 + ((kc*64 + lk*16) ^ swA));
        bf16x8 bh0 = Bhh[(unsigned)(((kc*2+0)*16 + wid*2+0)*64 + l)];
        bf16x8 bh1 = Bhh[(unsigned)(((kc*2+0)*16 + wid*2+1)*64 + l)];
        bf16x8 bl0 = Bhh[(unsigned)(((kc*2+1)*16 + wid*2+0)*64 + l)];
        bf16x8 bl1 = Bhh[(unsigned)(((kc*2+1)*16 + wid*2+1)*64 + l)];
        acc[s][0] = MFMA16(ah, bh0, acc[s][0]);
        acc[s][0] = MFMA16(al, bh0, acc[s][0]);
        acc[s][0] = MFMA16(ah, bl0, acc[s][0]);
        acc[s][1] = MFMA16(ah, bh1, acc[s][1]);
        acc[s][1] = MFMA16(al, bh1, acc[s][1]);
        acc[s][1] = MFMA16(ah, bl1, acc[s][1]);
      }
    }
    // write Z tile (C layout: row=lk*4+r, col=ln)
    #pragma unroll
    for (int nt=0;nt<2;++nt)
      #pragma unroll
      for (int r=0;r<4;++r)
        *(float*)(smem + (lk*4+r)*1024 + (n0 + nt*16 + ln)*4) = acc[s][nt][r];
    __syncthreads();
    // gates
    {
      float2 zi = *(float2*)(smem + gp*1024 +        gd*4);
      float2 zf = *(float2*)(smem + gp*1024 + 256  + gd*4);
      float2 zg = *(float2*)(smem + gp*1024 + 512  + gd*4);
      float2 zo = *(float2*)(smem + gp*1024 + 768  + gd*4);
      float i0 = sigm_f(zi.x), i1 = sigm_f(zi.y);
      float f0 = sigm_f(zf.x), f1 = sigm_f(zf.y);
      float g0 = tanh_f(zg.x), g1 = tanh_f(zg.y);
      float o0 = sigm_f(zo.x), o1 = sigm_f(zo.y);
      c0 = fmaf(f0, c0, i0*g0);
      c1 = fmaf(f1, c1, i1*g1);
      float h0 = o0 * tanh_f(c0);
      float h1 = o1 * tanh_f(c1);
      if (s == 3) *(float2*)(smem + HB + gp*256 + gd*4) = make_float2(h0, h1);
      unsigned short hh0,ll0,hh1,ll1;
      cvthl(h0, hh0, ll0); cvthl(h1, hh1, ll1);
      *(unsigned*)(smem + AHH + gp*128 + ((gd*2) ^ swg)) = (unsigned)hh0 | ((unsigned)hh1<<16);
      *(unsigned*)(smem + AHL + gp*128 + ((gd*2) ^ swg)) = (unsigned)ll0 | ((unsigned)ll1<<16);
    }
    __syncthreads();
  }

  // ---- attention hidden: relu(h @ BA + ctxp) -> overlays ZB  (waves 0..3, hi only)
  if (wid < 4){
    f32x4 acc2[2];
    #pragma unroll
    for (int nt=0;nt<2;++nt){
      float cv = ws[OFF_CTXP + wid*32 + nt*16 + ln];
      acc2[nt] = (f32x4){cv,cv,cv,cv};
    }
    #pragma unroll
    for (int kc=0;kc<2;++kc){
      bf16x8 ah = *(const bf16x8*)(smem + AHH + ln*128 + ((kc*64 + lk*16) ^ swA));
      bf16x8 bh0 = Bab[(unsigned)((kc*8 + wid*2+0)*64 + l)];
      bf16x8 bh1 = Bab[(unsigned)((kc*8 + wid*2+1)*64 + l)];
      acc2[0] = MFMA16(ah, bh0, acc2[0]);
      acc2[1] = MFMA16(ah, bh1, acc2[1]);
    }
    #pragma unroll
    for (int nt=0;nt<2;++nt)
      #pragma unroll
      for (int r=0;r<4;++r)
        *(float*)(smem + (lk*4+r)*512 + (wid*32 + nt*16 + ln)*4) = fmaxf(acc2[nt][r], 0.f);
  }
  __syncthreads();
  // ---- score = hidden . att_W2 + b2 ; e = exp(score)
  {
    int sp2 = t>>5, seg = t&31;
    float4 a = *(const float4*)(smem + sp2*512 + seg*16);
    float4 w = *(const float4*)(att_W2 + seg*4);
    float sc = a.x*w.x; sc = fmaf(a.y,w.y,sc); sc = fmaf(a.z,w.z,sc); sc = fmaf(a.w,w.w,sc);
    sc += __shfl_xor(sc,1); sc += __shfl_xor(sc,2); sc += __shfl_xor(sc,4);
    sc += __shfl_xor(sc,8); sc += __shfl_xor(sc,16);
    if (seg == 0){
      float e = __expf(sc + att_b2[0]);
      *(float*)(smem + ESO + sp2*4) = e;
      ws[OFF_E + p0 + sp2] = e;
    }
  }
  __syncthreads();
  // ---- partial sums: sum(e), sum(e*h)
  {
    int pg = t>>6, d = t&63;
    const float* es = (const float*)(smem + ESO);
    float a = es[pg*2]   * (*(const float*)(smem + HB + (pg*2  )*256 + d*4))
            + es[pg*2+1] * (*(const float*)(smem + HB + (pg*2+1)*256 + d*4));
    *(float*)(smem + PARTO + (pg*64+d)*4) = a;
  }
  __syncthreads();
  if (t < 64){
    const float* part = (const float*)(smem + PARTO);
    float a = 0.f;
    #pragma unroll
    for (int pg=0;pg<8;++pg) a += part[pg*64 + t];
    ws[OFF_PAGG + bid*64 + t] = a;
  }
  if (t < 16){
    float e2 = *(const float*)(smem + ESO + t*4);
    e2 += __shfl_xor(e2,1); e2 += __shfl_xor(e2,2);
    e2 += __shfl_xor(e2,4); e2 += __shfl_xor(e2,8);
    if (t==0) ws[OFF_PE + bid] = e2;
  }
}

// ---------------------------------------------------------------- reduce stage A: 64 blocks
__global__ __launch_bounds__(256) void kredA(float* __restrict__ ws)
{
  const float* p_e   = ws + OFF_PE;
  const float* p_agg = ws + OFF_PAGG;
  __shared__ float red[256];
  const int b = blockIdx.x, t = threadIdx.x;
  const int s = b*4 + (t>>6), d = t&63;
  float a = 0.f;
  for (int row = s; row < NBLK; row += 256) a += p_agg[row*64 + d];
  ws[OFF_P2AGG + s*64 + d] = a;
  float pe = 0.f;
  {
    int i = b*98 + t;
    if (t < 98 && i < NBLK) pe = p_e[i];
  }
  pe += __shfl_xor(pe,1); pe += __shfl_xor(pe,2); pe += __shfl_xor(pe,4);
  pe += __shfl_xor(pe,8); pe += __shfl_xor(pe,16); pe += __shfl_xor(pe,32);
  if ((t&63)==0) red[t>>6] = pe;
  __syncthreads();
  if (t==0) ws[OFF_P2E + b] = red[0]+red[1]+red[2]+red[3];
}

// ---------------------------------------------------------------- reduce stage B + heads: 1 block
__global__ __launch_bounds__(256) void kredB(
    const float* __restrict__ val_W1, const float* __restrict__ val_b1,
    const float* __restrict__ val_W2, const float* __restrict__ val_b2,
    float* __restrict__ ws, float* __restrict__ d_out)
{
  __shared__ float aggL[64];
  __shared__ float red[256];
  __shared__ float Zs;
  const int t = threadIdx.x;
  {
    float pe = (t < 64) ? ws[OFF_P2E + t] : 0.f;
    pe += __shfl_xor(pe,1); pe += __shfl_xor(pe,2); pe += __shfl_xor(pe,4);
    pe += __shfl_xor(pe,8); pe += __shfl_xor(pe,16); pe += __shfl_xor(pe,32);
    if (t==0){ Zs = pe; ws[OFF_MISC+1] = 1.f/pe; }
  }
  {
    int d = t&63, q = t>>6;
    float a = 0.f;
    #pragma unroll 4
    for (int s2=q; s2<256; s2+=4) a += ws[OFF_P2AGG + s2*64 + d];
    red[t] = a;
  }
  __syncthreads();
  if (t < 64) aggL[t] = (red[t] + red[64+t] + red[128+t] + red[192+t]) / Zs;
  __syncthreads();
  if (t < 32){
    float hv = val_b1[t];
    for (int k=0;k<64;++k) hv = fmaf(aggL[k], val_W1[t*64+k], hv);
    hv = fmaxf(hv, 0.f);
    float v = hv * val_W2[t];
    v += __shfl_xor(v,1); v += __shfl_xor(v,2); v += __shfl_xor(v,4);
    v += __shfl_xor(v,8); v += __shfl_xor(v,16);
    // q_value = value + (advantage - mean(advantage)) == value (advantage is [1])
    if (t==0) d_out[0] = (v + val_b2[0]) * ws[OFF_MISC+0];
  }
}

// ---------------------------------------------------------------- att weights out
__global__ __launch_bounds__(256) void kweights(
    const float* __restrict__ ws, float* __restrict__ d_out)
{
  int p = blockIdx.x*256 + threadIdx.x;
  if (p < P_TOT) d_out[1+p] = ws[OFF_E + p] * ws[OFF_MISC+1];
}

// ---------------------------------------------------------------- launch
extern "C" void kernel_launch(void* const* d_in, const int* in_sizes, int n_in,
                              void* d_out, int out_size, void* d_ws, size_t ws_size,
                              hipStream_t stream) {
  const int*   user_idx   = (const int*)  d_in[0];
  const int*   item_idx   = (const int*)  d_in[1];
  const int*   node_ids   = (const int*)  d_in[2];
  const int*   node_types = (const int*)  d_in[3];
  const int*   rel_idx    = (const int*)  d_in[4];
  const float* user_emb   = (const float*)d_in[5];
  const float* item_emb   = (const float*)d_in[6];
  const float* rel_emb    = (const float*)d_in[7];
  const float* ntype_emb  = (const float*)d_in[8];
  const float* W_ih       = (const float*)d_in[9];
  const float* W_hh       = (const float*)d_in[10];
  const float* b_ih       = (const float*)d_in[11];
  const float* b_hh       = (const float*)d_in[12];
  const float* att_W1     = (const float*)d_in[13];
  const float* att_b1     = (const float*)d_in[14];
  const float* att_W2     = (const float*)d_in[15];
  const float* att_b2     = (const float*)d_in[16];
  const float* val_W1     = (const float*)d_in[17];
  const float* val_b1     = (const float*)d_in[18];
  const float* val_W2     = (const float*)d_in[19];
  const float* val_b2     = (const float*)d_in[20];
  const float* saf_W1     = (const float*)d_in[25];
  const float* saf_b1     = (const float*)d_in[26];
  const float* saf_W2     = (const float*)d_in[27];
  const float* saf_b2     = (const float*)d_in[28];
  float* ws  = (float*)d_ws;
  float* out = (float*)d_out;

  const bool fast = (ws_size >= WS_FAST_BYTES);

  hipLaunchKernelGGL(kprep, dim3(64), dim3(256), 0, stream,
                     user_idx, item_idx, user_emb, item_emb,
                     W_ih, W_hh, b_ih, b_hh, att_W1, att_b1,
                     saf_W1, saf_b1, saf_W2, saf_b2, ws);
  if (fast){
    hipLaunchKernelGGL(kconv, dim3((150010*8+255)/256), dim3(256), 0, stream,
                       user_emb, item_emb, rel_emb, ntype_emb, ws);
    hipLaunchKernelGGL(klstm<1>, dim3(NBLK), dim3(512), 0, stream,
                       node_ids, node_types, rel_idx,
                       user_emb, item_emb, rel_emb, ntype_emb,
                       att_W2, att_b2, ws);
  } else {
    hipLaunchKernelGGL(klstm<0>, dim3(NBLK), dim3(512), 0, stream,
                       node_ids, node_types, rel_idx,
                       user_emb, item_emb, rel_emb, ntype_emb,
                       att_W2, att_b2, ws);
  }
  hipLaunchKernelGGL(kredA, dim3(64), dim3(256), 0, stream, ws);
  hipLaunchKernelGGL(kredB, dim3(1), dim3(256), 0, stream,
                     val_W1, val_b1, val_W2, val_b2, ws, out);
  hipLaunchKernelGGL(kweights, dim3((P_TOT+255)/256), dim3(256), 0, stream,
                     ws, out);
}

// Round 9
// 150.452 us; speedup vs baseline: 2.1907x; 1.1474x over previous
//
#include <hip/hip_runtime.h>
#include <math.h>

#define P_TOT 100000
#define BM    16
#define NBLK  6250

// ws float offsets
#define OFF_BIH   0        // 24576: 96 frags (6kc x 8w x 2nt) x 1KB, GATE-PERMUTED cols, hi only
#define OFF_BHH   24576    // 8192: 32 frags (2kc x 8w x 2nt), gate-permuted, hi only
#define OFF_BA    32768    // 4096: 16 frags (2kc x 8ntg), standard cols, hi only
#define OFF_BSUM  36864    // 256 (natural order)
#define OFF_CTXP  37120    // 128
#define OFF_MISC  37248    // [0]=safety, [1]=invZ
#define OFF_E     37264    // 100000
#define OFF_PE    137264   // 6250
#define OFF_PAGG  143520   // 6250*64
#define OFF_P2E   543520   // 64
#define OFF_P2AGG 543584   // 256*64
// hi-only bf16 embedding tables: [row][128B] = 32 f32-slots/row
#define OFF_TAB   560000
#define OFF_TU    (OFF_TAB)                 // 100000 rows
#define OFF_TI    (OFF_TAB + 3200000)       // 50000 rows
#define OFF_TR    (OFF_TAB + 4800000)       // 8 rows
#define OFF_TT    (OFF_TAB + 4800256)       // 2 rows
#define WS_FAST_BYTES ((size_t)(OFF_TAB + 4800320) * 4)

// klstm LDS (34880 B):
//  AF  @0     (24576): [4s][16p]x384B hi-only swizzled A tiles (phase1); attn HIDB overlays @0
//  AHB @24576 (4096): 2 x [16p]x128B h bf16, double-buffered, swizzled
//  HB  @28672 (4096): h_n f32 [16p][64d]
//  ES  @32768 (64) | PART @32832 (2048)
#define AHB   24576
#define HBO   28672
#define ESO   32768
#define PARTO 32832
#define LDS_BYTES 34880

typedef short bf16x8 __attribute__((ext_vector_type(8)));
typedef float f32x4  __attribute__((ext_vector_type(4)));

#define MFMA16(a,b,c) __builtin_amdgcn_mfma_f32_16x16x32_bf16((a),(b),(c),0,0,0)

__device__ __forceinline__ unsigned short cvh(float v){
  unsigned int u = __float_as_uint(v);
  return (unsigned short)((u + 0x7fffu + ((u>>16)&1u)) >> 16);
}
__device__ __forceinline__ float sigm_f(float x){ return 1.f/(1.f+__expf(-x)); }
__device__ __forceinline__ float tanh_f(float x){
  float e2 = __expf(2.f*x);
  return (e2-1.f)/(e2+1.f);
}

// ---------------------------------------------------------------- prep (weights)
__global__ __launch_bounds__(256) void kprep(
    const int* __restrict__ user_idx, const int* __restrict__ item_idx,
    const float* __restrict__ user_emb, const float* __restrict__ item_emb,
    const float* __restrict__ W_ih, const float* __restrict__ W_hh,
    const float* __restrict__ b_ih, const float* __restrict__ b_hh,
    const float* __restrict__ att_W1, const float* __restrict__ att_b1,
    const float* __restrict__ saf_W1, const float* __restrict__ saf_b1,
    const float* __restrict__ saf_W2, const float* __restrict__ saf_b2,
    float* __restrict__ ws)
{
  const int t = threadIdx.x;
  for (int fb = blockIdx.x; fb < 144; fb += gridDim.x){
    const float* src; int base, rowlen, kc; bool perm; int w=0, nt=0, ntg=0;
    if (fb < 96){ kc = fb>>4; int rem = fb&15; w = rem>>1; nt = rem&1; perm = true;
                  base = OFF_BIH + fb*256; src = W_ih; rowlen = 192; }
    else if (fb < 128){ int f2 = fb-96; kc = f2>>4; int rem = f2&15; w = rem>>1; nt = rem&1; perm = true;
                  base = OFF_BHH + f2*256; src = W_hh; rowlen = 64; }
    else { int f3 = fb-128; kc = f3>>3; ntg = f3&7; perm = false;
                  base = OFF_BA + f3*256; src = att_W1; rowlen = 192; }
    unsigned short* dst = (unsigned short*)(ws + base);
    for (int e = t; e < 512; e += 256){
      int l = e>>3, j = e&7;
      int c = l&15;
      int n = perm ? (nt*2 + (c>>3))*64 + w*8 + (c&7)
                   : ntg*16 + c;
      int k = kc*32 + (l>>4)*8 + j;
      dst[e] = cvh(src[n*rowlen + k]);
    }
  }
  if (blockIdx.x == 0){
    __shared__ float ctx[128];
    if (t < 256) ws[OFF_BSUM+t] = b_ih[t] + b_hh[t];
    if (t < 64){
      ctx[t]    = user_emb[user_idx[0]*64 + t];
      ctx[64+t] = item_emb[item_idx[0]*64 + t];
    }
    __syncthreads();
    if (t < 128){
      float s = att_b1[t];
      for (int k=0;k<128;++k) s = fmaf(att_W1[t*192 + 64 + k], ctx[k], s);
      ws[OFF_CTXP + t] = s;
    }
    if (t < 32){
      float s = saf_b1[t];
      for (int k=0;k<128;++k) s = fmaf(saf_W1[t*128+k], ctx[k], s);
      s = fmaxf(s, 0.f);
      float v = s * saf_W2[t];
      v += __shfl_xor(v,1); v += __shfl_xor(v,2); v += __shfl_xor(v,4);
      v += __shfl_xor(v,8); v += __shfl_xor(v,16);
      if (t==0) ws[OFF_MISC+0] = 1.f/(1.f+expf(-(v + saf_b2[0])));
    }
  }
}

// ---------------------------------------------------------------- table conversion (hi-only)
__global__ __launch_bounds__(256) void kconv(
    const float* __restrict__ user_emb, const float* __restrict__ item_emb,
    const float* __restrict__ relation_emb, const float* __restrict__ node_type_emb,
    float* __restrict__ ws)
{
  const int gid = blockIdx.x*256 + threadIdx.x;
  const int row = gid >> 3, seg = gid & 7;
  if (row >= 150010) return;
  const float* src; int dstoff;
  if (row < 100000){ src = user_emb + row*64;             dstoff = OFF_TU + row*32; }
  else if (row < 150000){ src = item_emb + (row-100000)*64; dstoff = OFF_TI + (row-100000)*32; }
  else if (row < 150008){ src = relation_emb + (row-150000)*64; dstoff = OFF_TR + (row-150000)*32; }
  else { src = node_type_emb + (row-150008)*64;           dstoff = OFF_TT + (row-150008)*32; }
  float4 v0 = ((const float4*)(src + seg*8))[0];
  float4 v1 = ((const float4*)(src + seg*8))[1];
  uint4 hq;
  hq.x = (unsigned)cvh(v0.x) | ((unsigned)cvh(v0.y)<<16);
  hq.y = (unsigned)cvh(v0.z) | ((unsigned)cvh(v0.w)<<16);
  hq.z = (unsigned)cvh(v1.x) | ((unsigned)cvh(v1.y)<<16);
  hq.w = (unsigned)cvh(v1.z) | ((unsigned)cvh(v1.w)<<16);
  *(uint4*)((char*)(ws + dstoff) + seg*16) = hq;
}

// ---------------------------------------------------------------- main: LSTM + attention
// gate-permuted cols -> gates from registers via shfl_xor(8); single-bf16 throughout
template<int PRE>
__global__ __launch_bounds__(512,4) void klstm(
    const int* __restrict__ node_ids, const int* __restrict__ node_types,
    const int* __restrict__ rel_idx,
    const float* __restrict__ user_emb, const float* __restrict__ item_emb,
    const float* __restrict__ relation_emb, const float* __restrict__ node_type_emb,
    const float* __restrict__ att_W2, const float* __restrict__ att_b2,
    float* __restrict__ ws)
{
  __shared__ __align__(16) unsigned char smem[LDS_BYTES];
  const int t   = threadIdx.x;
  const int l   = t & 63, wid = t >> 6;
  const int ln  = l & 15, lk = l >> 4;
  const int bid = blockIdx.x, p0 = bid*BM;
  const bf16x8* Bih = (const bf16x8*)(ws + OFF_BIH);
  const bf16x8* Bhh = (const bf16x8*)(ws + OFF_BHH);
  const bf16x8* Bab = (const bf16x8*)(ws + OFF_BA);
  const int swA = (ln&7)<<4;

  // ---- gather feats (all 4 steps, hi only) -> swizzled bf16 A tiles
  if (t < 384){
    int r = t>>1, half = t&1;
    int s = r/48, rem = r - s*48, src = rem>>4, p = rem&15;
    int gi = (p0+p)*4 + s;
    const int sw = (p&7)<<4;
    const int row = (s*16 + p)*384;
    if (PRE){
      const char* rp;
      if (src==0){ int nid = node_ids[gi];
                   rp = (const char*)(ws + (node_types[gi]==0 ? OFF_TU + nid*32 : OFF_TI + nid*32)); }
      else if (src==1){ rp = (const char*)(ws + OFF_TT + node_types[gi]*32); }
      else { rp = (const char*)(ws + OFF_TR + rel_idx[gi]*32); }
      #pragma unroll
      for (int ii=0; ii<4; ++ii){
        int i = half*4 + ii;
        uint4 hq = *(const uint4*)(rp + i*16);
        *(uint4*)(smem + row + ((src*128 + i*16) ^ sw)) = hq;
      }
    } else {
      const float* sp;
      if (src==0){ int nid = node_ids[gi]; sp = (node_types[gi]==0 ? user_emb : item_emb) + nid*64; }
      else if (src==1){ sp = node_type_emb + node_types[gi]*64; }
      else { sp = relation_emb + rel_idx[gi]*64; }
      #pragma unroll
      for (int ii=0; ii<4; ++ii){
        int i = half*4 + ii;
        float4 v0 = ((const float4*)sp)[i*2];
        float4 v1 = ((const float4*)sp)[i*2+1];
        uint4 hq;
        hq.x = (unsigned)cvh(v0.x) | ((unsigned)cvh(v0.y)<<16);
        hq.y = (unsigned)cvh(v0.z) | ((unsigned)cvh(v0.w)<<16);
        hq.z = (unsigned)cvh(v1.x) | ((unsigned)cvh(v1.y)<<16);
        hq.w = (unsigned)cvh(v1.z) | ((unsigned)cvh(v1.w)<<16);
        *(uint4*)(smem + row + ((src*128 + i*16) ^ sw)) = hq;
      }
    }
  }
  // ---- acc init with bias (permuted cols)
  f32x4 acc[4][2];
  {
    float bv0 = ws[OFF_BSUM + ((ln>>3))*64   + wid*8 + (ln&7)];        // nt=0
    float bv1 = ws[OFF_BSUM + (2+(ln>>3))*64 + wid*8 + (ln&7)];        // nt=1
    #pragma unroll
    for (int s=0;s<4;++s){
      acc[s][0] = (f32x4){bv0,bv0,bv0,bv0};
      acc[s][1] = (f32x4){bv1,bv1,bv1,bv1};
    }
  }
  __syncthreads();

  // ---- phase 1: Zfeat for all 4 steps (K=192)
  #pragma unroll 2
  for (int kc=0;kc<6;++kc){
    bf16x8 bh0 = Bih[(unsigned)((kc*16 + wid*2+0)*64 + l)];
    bf16x8 bh1 = Bih[(unsigned)((kc*16 + wid*2+1)*64 + l)];
    #pragma unroll
    for (int s=0;s<4;++s){
      bf16x8 ah = *(const bf16x8*)(smem + (s*16+ln)*384 + ((kc*64 + lk*16) ^ swA));
      acc[s][0] = MFMA16(ah, bh0, acc[s][0]);
      acc[s][1] = MFMA16(ah, bh1, acc[s][1]);
    }
  }

  // ---- phase 2: recurrence, gates from registers
  const int hi8 = ln>>3;              // 0: holds (i,g) rows 0-3; 1: holds (f,o)
  const int dd  = wid*8 + (ln&7);     // dim
  const int pth0 = lk*4 + hi8*2, pth1 = pth0 + 1;
  const int ahw0 = AHB + pth0*128 + ((dd*2) ^ ((pth0&7)<<4));
  const int ahw1 = AHB + pth1*128 + ((dd*2) ^ ((pth1&7)<<4));
  float c0 = 0.f, c1 = 0.f;
  #pragma unroll
  for (int s=0;s<4;++s){
    if (s > 0){
      const int rb = AHB + ((s&1))*2048;
      #pragma unroll
      for (int kc=0;kc<2;++kc){
        bf16x8 ah = *(const bf16x8*)(smem + rb + ln*128 + ((kc*64 + lk*16) ^ swA));
        bf16x8 bh0 = Bhh[(unsigned)((kc*16 + wid*2+0)*64 + l)];
        bf16x8 bh1 = Bhh[(unsigned)((kc*16 + wid*2+1)*64 + l)];
        acc[s][0] = MFMA16(ah, bh0, acc[s][0]);
        acc[s][1] = MFMA16(ah, bh1, acc[s][1]);
      }
    }
    // exchange with partner lane (ln^8): all 4 gates for this lane's dim
    float a00 = acc[s][0][0], a01 = acc[s][0][1], a02 = acc[s][0][2], a03 = acc[s][0][3];
    float a10 = acc[s][1][0], a11 = acc[s][1][1], a12 = acc[s][1][2], a13 = acc[s][1][3];
    float p00 = __shfl_xor(a00,8), p01 = __shfl_xor(a01,8);
    float p02 = __shfl_xor(a02,8), p03 = __shfl_xor(a03,8);
    float p10 = __shfl_xor(a10,8), p11 = __shfl_xor(a11,8);
    float p12 = __shfl_xor(a12,8), p13 = __shfl_xor(a13,8);
    float vi0 = hi8 ? p02 : a00;  float vf0 = hi8 ? a02 : p00;
    float vg0 = hi8 ? p12 : a10;  float vo0 = hi8 ? a12 : p10;
    float vi1 = hi8 ? p03 : a01;  float vf1 = hi8 ? a03 : p01;
    float vg1 = hi8 ? p13 : a11;  float vo1 = hi8 ? a13 : p11;
    float i0 = sigm_f(vi0), f0 = sigm_f(vf0), g0 = tanh_f(vg0), o0 = sigm_f(vo0);
    float i1 = sigm_f(vi1), f1 = sigm_f(vf1), g1 = tanh_f(vg1), o1 = sigm_f(vo1);
    c0 = fmaf(f0, c0, i0*g0);
    c1 = fmaf(f1, c1, i1*g1);
    float h0 = o0 * tanh_f(c0);
    float h1 = o1 * tanh_f(c1);
    if (s == 3){
      *(float*)(smem + HBO + pth0*256 + dd*4) = h0;
      *(float*)(smem + HBO + pth1*256 + dd*4) = h1;
    }
    const int wb = ((s&1)^1)*2048;
    *(unsigned short*)(smem + ahw0 + wb) = cvh(h0);
    *(unsigned short*)(smem + ahw1 + wb) = cvh(h1);
    __syncthreads();
  }

  // ---- attention hidden: relu(h @ BA + ctxp) -> HIDB overlays AF@0  (waves 0..3)
  if (wid < 4){
    f32x4 acc2[2];
    #pragma unroll
    for (int nt=0;nt<2;++nt){
      float cv = ws[OFF_CTXP + wid*32 + nt*16 + ln];
      acc2[nt] = (f32x4){cv,cv,cv,cv};
    }
    #pragma unroll
    for (int kc=0;kc<2;++kc){
      bf16x8 ah = *(const bf16x8*)(smem + AHB + ln*128 + ((kc*64 + lk*16) ^ swA));  // buf0 = h_n
      bf16x8 bh0 = Bab[(unsigned)((kc*8 + wid*2+0)*64 + l)];
      bf16x8 bh1 = Bab[(unsigned)((kc*8 + wid*2+1)*64 + l)];
      acc2[0] = MFMA16(ah, bh0, acc2[0]);
      acc2[1] = MFMA16(ah, bh1, acc2[1]);
    }
    #pragma unroll
    for (int nt=0;nt<2;++nt)
      #pragma unroll
      for (int r=0;r<4;++r)
        *(float*)(smem + (lk*4+r)*512 + (wid*32 + nt*16 + ln)*4) = fmaxf(acc2[nt][r], 0.f);
  }
  __syncthreads();
  // ---- score = hidden . att_W2 + b2 ; e = exp(score)
  {
    int sp2 = t>>5, seg = t&31;
    float4 a = *(const float4*)(smem + sp2*512 + seg*16);
    float4 w = *(const float4*)(att_W2 + seg*4);
    float sc = a.x*w.x; sc = fmaf(a.y,w.y,sc); sc = fmaf(a.z,w.z,sc); sc = fmaf(a.w,w.w,sc);
    sc += __shfl_xor(sc,1); sc += __shfl_xor(sc,2); sc += __shfl_xor(sc,4);
    sc += __shfl_xor(sc,8); sc += __shfl_xor(sc,16);
    if (seg == 0){
      float e = __expf(sc + att_b2[0]);
      *(float*)(smem + ESO + sp2*4) = e;
      ws[OFF_E + p0 + sp2] = e;
    }
  }
  __syncthreads();
  // ---- partial sums: sum(e), sum(e*h)
  {
    int pg = t>>6, d = t&63;
    const float* es = (const float*)(smem + ESO);
    float a = es[pg*2]   * (*(const float*)(smem + HBO + (pg*2  )*256 + d*4))
            + es[pg*2+1] * (*(const float*)(smem + HBO + (pg*2+1)*256 + d*4));
    *(float*)(smem + PARTO + (pg*64+d)*4) = a;
  }
  __syncthreads();
  if (t < 64){
    const float* part = (const float*)(smem + PARTO);
    float a = 0.f;
    #pragma unroll
    for (int pg=0;pg<8;++pg) a += part[pg*64 + t];
    ws[OFF_PAGG + bid*64 + t] = a;
  }
  if (t < 16){
    float e2 = *(const float*)(smem + ESO + t*4);
    e2 += __shfl_xor(e2,1); e2 += __shfl_xor(e2,2);
    e2 += __shfl_xor(e2,4); e2 += __shfl_xor(e2,8);
    if (t==0) ws[OFF_PE + bid] = e2;
  }
}

// ---------------------------------------------------------------- reduce stage A: 64 blocks
__global__ __launch_bounds__(256) void kredA(float* __restrict__ ws)
{
  const float* p_e   = ws + OFF_PE;
  const float* p_agg = ws + OFF_PAGG;
  __shared__ float red[256];
  const int b = blockIdx.x, t = threadIdx.x;
  const int s = b*4 + (t>>6), d = t&63;
  float a = 0.f;
  for (int row = s; row < NBLK; row += 256) a += p_agg[row*64 + d];
  ws[OFF_P2AGG + s*64 + d] = a;
  float pe = 0.f;
  {
    int i = b*98 + t;
    if (t < 98 && i < NBLK) pe = p_e[i];
  }
  pe += __shfl_xor(pe,1); pe += __shfl_xor(pe,2); pe += __shfl_xor(pe,4);
  pe += __shfl_xor(pe,8); pe += __shfl_xor(pe,16); pe += __shfl_xor(pe,32);
  if ((t&63)==0) red[t>>6] = pe;
  __syncthreads();
  if (t==0) ws[OFF_P2E + b] = red[0]+red[1]+red[2]+red[3];
}

// ---------------------------------------------------------------- reduce stage B + heads: 1 block
__global__ __launch_bounds__(256) void kredB(
    const float* __restrict__ val_W1, const float* __restrict__ val_b1,
    const float* __restrict__ val_W2, const float* __restrict__ val_b2,
    float* __restrict__ ws, float* __restrict__ d_out)
{
  __shared__ float aggL[64];
  __shared__ float red[256];
  __shared__ float Zs;
  const int t = threadIdx.x;
  {
    float pe = (t < 64) ? ws[OFF_P2E + t] : 0.f;
    pe += __shfl_xor(pe,1); pe += __shfl_xor(pe,2); pe += __shfl_xor(pe,4);
    pe += __shfl_xor(pe,8); pe += __shfl_xor(pe,16); pe += __shfl_xor(pe,32);
    if (t==0){ Zs = pe; ws[OFF_MISC+1] = 1.f/pe; }
  }
  {
    int d = t&63, q = t>>6;
    float a = 0.f;
    #pragma unroll 4
    for (int s2=q; s2<256; s2+=4) a += ws[OFF_P2AGG + s2*64 + d];
    red[t] = a;
  }
  __syncthreads();
  if (t < 64) aggL[t] = (red[t] + red[64+t] + red[128+t] + red[192+t]) / Zs;
  __syncthreads();
  if (t < 32){
    float hv = val_b1[t];
    for (int k=0;k<64;++k) hv = fmaf(aggL[k], val_W1[t*64+k], hv);
    hv = fmaxf(hv, 0.f);
    float v = hv * val_W2[t];
    v += __shfl_xor(v,1); v += __shfl_xor(v,2); v += __shfl_xor(v,4);
    v += __shfl_xor(v,8); v += __shfl_xor(v,16);
    // q_value = value + (advantage - mean(advantage)) == value (advantage is [1])
    if (t==0) d_out[0] = (v + val_b2[0]) * ws[OFF_MISC+0];
  }
}

// ---------------------------------------------------------------- att weights out
__global__ __launch_bounds__(256) void kweights(
    const float* __restrict__ ws, float* __restrict__ d_out)
{
  int p = blockIdx.x*256 + threadIdx.x;
  if (p < P_TOT) d_out[1+p] = ws[OFF_E + p] * ws[OFF_MISC+1];
}

// ---------------------------------------------------------------- launch
extern "C" void kernel_launch(void* const* d_in, const int* in_sizes, int n_in,
                              void* d_out, int out_size, void* d_ws, size_t ws_size,
                              hipStream_t stream) {
  const int*   user_idx   = (const int*)  d_in[0];
  const int*   item_idx   = (const int*)  d_in[1];
  const int*   node_ids   = (const int*)  d_in[2];
  const int*   node_types = (const int*)  d_in[3];
  const int*   rel_idx    = (const int*)  d_in[4];
  const float* user_emb   = (const float*)d_in[5];
  const float* item_emb   = (const float*)d_in[6];
  const float* rel_emb    = (const float*)d_in[7];
  const float* ntype_emb  = (const float*)d_in[8];
  const float* W_ih       = (const float*)d_in[9];
  const float* W_hh       = (const float*)d_in[10];
  const float* b_ih       = (const float*)d_in[11];
  const float* b_hh       = (const float*)d_in[12];
  const float* att_W1     = (const float*)d_in[13];
  const float* att_b1     = (const float*)d_in[14];
  const float* att_W2     = (const float*)d_in[15];
  const float* att_b2     = (const float*)d_in[16];
  const float* val_W1     = (const float*)d_in[17];
  const float* val_b1     = (const float*)d_in[18];
  const float* val_W2     = (const float*)d_in[19];
  const float* val_b2     = (const float*)d_in[20];
  const float* saf_W1     = (const float*)d_in[25];
  const float* saf_b1     = (const float*)d_in[26];
  const float* saf_W2     = (const float*)d_in[27];
  const float* saf_b2     = (const float*)d_in[28];
  float* ws  = (float*)d_ws;
  float* out = (float*)d_out;

  const bool fast = (ws_size >= WS_FAST_BYTES);

  hipLaunchKernelGGL(kprep, dim3(64), dim3(256), 0, stream,
                     user_idx, item_idx, user_emb, item_emb,
                     W_ih, W_hh, b_ih, b_hh, att_W1, att_b1,
                     saf_W1, saf_b1, saf_W2, saf_b2, ws);
  if (fast){
    hipLaunchKernelGGL(kconv, dim3((150010*8+255)/256), dim3(256), 0, stream,
                       user_emb, item_emb, rel_emb, ntype_emb, ws);
    hipLaunchKernelGGL(klstm<1>, dim3(NBLK), dim3(512), 0, stream,
                       node_ids, node_types, rel_idx,
                       user_emb, item_emb, rel_emb, ntype_emb,
                       att_W2, att_b2, ws);
  } else {
    hipLaunchKernelGGL(klstm<0>, dim3(NBLK), dim3(512), 0, stream,
                       node_ids, node_types, rel_idx,
                       user_emb, item_emb, rel_emb, ntype_emb,
                       att_W2, att_b2, ws);
  }
  hipLaunchKernelGGL(kredA, dim3(64), dim3(256), 0, stream, ws);
  hipLaunchKernelGGL(kredB, dim3(1), dim3(256), 0, stream,
                     val_W1, val_b1, val_W2, val_b2, ws, out);
  hipLaunchKernelGGL(kweights, dim3((P_TOT+255)/256), dim3(256), 0, stream,
                     ws, out);
}

// Round 10
// 144.104 us; speedup vs baseline: 2.2872x; 1.0441x over previous
//
#include <hip/hip_runtime.h>
#include <math.h>

#define P_TOT 100000
#define BM    32
#define NBLK  3125

// ws float offsets
#define OFF_BIH   0        // 96 frags (6kc x 8w x 2nt) x 1KB, GATE-PERMUTED cols, hi only
#define OFF_BHH   24576    // 32 frags (2kc x 8w x 2nt), gate-permuted, hi only
#define OFF_BA    32768    // 16 frags (2kc x 8ntg), standard cols, hi only
#define OFF_BSUM  36864    // 256 (natural order)
#define OFF_CTXP  37120    // 128
#define OFF_MISC  37248    // [0]=safety, [1]=invZ
#define OFF_E     37264    // 100000
#define OFF_PE    137264   // 3125
#define OFF_PAGG  140392   // 3125*64
#define OFF_P2E   340392   // 64
#define OFF_P2AGG 340456   // 256*64
// hi-only bf16 embedding tables: [row][128B] = 32 f32-slots/row
#define OFF_TAB   356864
#define OFF_TU    (OFF_TAB)                 // 100000 rows
#define OFF_TI    (OFF_TAB + 3200000)       // 50000 rows
#define OFF_TR    (OFF_TAB + 4800000)       // 8 rows
#define OFF_TT    (OFF_TAB + 4800256)       // 2 rows
#define WS_FAST_BYTES ((size_t)(OFF_TAB + 4800320) * 4)

// klstm LDS (59520 B):
//  AF  @0     (49152): [4s][32p]x384B hi-only swizzled A tiles; attn HIDB (16KB) overlays @0
//  AHB @49152 (8192): 2 x [32p]x128B h bf16, double-buffered, swizzled
//  ES  @57344 (128) | PART @57472 (2048)
#define AHB   49152
#define ESO   57344
#define PARTO 57472
#define LDS_BYTES 59520

typedef short bf16x8 __attribute__((ext_vector_type(8)));
typedef float f32x4  __attribute__((ext_vector_type(4)));

#define MFMA16(a,b,c) __builtin_amdgcn_mfma_f32_16x16x32_bf16((a),(b),(c),0,0,0)

__device__ __forceinline__ unsigned short cvh(float v){
  unsigned int u = __float_as_uint(v);
  return (unsigned short)((u + 0x7fffu + ((u>>16)&1u)) >> 16);
}
__device__ __forceinline__ float sigm_f(float x){ return 1.f/(1.f+__expf(-x)); }
__device__ __forceinline__ float tanh_f(float x){
  float e2 = __expf(2.f*x);
  return (e2-1.f)/(e2+1.f);
}

// ---------------------------------------------------------------- prep (weights)
__global__ __launch_bounds__(256) void kprep(
    const int* __restrict__ user_idx, const int* __restrict__ item_idx,
    const float* __restrict__ user_emb, const float* __restrict__ item_emb,
    const float* __restrict__ W_ih, const float* __restrict__ W_hh,
    const float* __restrict__ b_ih, const float* __restrict__ b_hh,
    const float* __restrict__ att_W1, const float* __restrict__ att_b1,
    const float* __restrict__ saf_W1, const float* __restrict__ saf_b1,
    const float* __restrict__ saf_W2, const float* __restrict__ saf_b2,
    float* __restrict__ ws)
{
  const int t = threadIdx.x;
  for (int fb = blockIdx.x; fb < 144; fb += gridDim.x){
    const float* src; int base, rowlen, kc; bool perm; int w=0, nt=0, ntg=0;
    if (fb < 96){ kc = fb>>4; int rem = fb&15; w = rem>>1; nt = rem&1; perm = true;
                  base = OFF_BIH + fb*256; src = W_ih; rowlen = 192; }
    else if (fb < 128){ int f2 = fb-96; kc = f2>>4; int rem = f2&15; w = rem>>1; nt = rem&1; perm = true;
                  base = OFF_BHH + f2*256; src = W_hh; rowlen = 64; }
    else { int f3 = fb-128; kc = f3>>3; ntg = f3&7; perm = false;
                  base = OFF_BA + f3*256; src = att_W1; rowlen = 192; }
    unsigned short* dst = (unsigned short*)(ws + base);
    for (int e = t; e < 512; e += 256){
      int l = e>>3, j = e&7;
      int c = l&15;
      int n = perm ? (nt*2 + (c>>3))*64 + w*8 + (c&7)
                   : ntg*16 + c;
      int k = kc*32 + (l>>4)*8 + j;
      dst[e] = cvh(src[n*rowlen + k]);
    }
  }
  if (blockIdx.x == 0){
    __shared__ float ctx[128];
    if (t < 256) ws[OFF_BSUM+t] = b_ih[t] + b_hh[t];
    if (t < 64){
      ctx[t]    = user_emb[user_idx[0]*64 + t];
      ctx[64+t] = item_emb[item_idx[0]*64 + t];
    }
    __syncthreads();
    if (t < 128){
      float s = att_b1[t];
      for (int k=0;k<128;++k) s = fmaf(att_W1[t*192 + 64 + k], ctx[k], s);
      ws[OFF_CTXP + t] = s;
    }
    if (t < 32){
      float s = saf_b1[t];
      for (int k=0;k<128;++k) s = fmaf(saf_W1[t*128+k], ctx[k], s);
      s = fmaxf(s, 0.f);
      float v = s * saf_W2[t];
      v += __shfl_xor(v,1); v += __shfl_xor(v,2); v += __shfl_xor(v,4);
      v += __shfl_xor(v,8); v += __shfl_xor(v,16);
      if (t==0) ws[OFF_MISC+0] = 1.f/(1.f+expf(-(v + saf_b2[0])));
    }
  }
}

// ---------------------------------------------------------------- table conversion (hi-only)
__global__ __launch_bounds__(256) void kconv(
    const float* __restrict__ user_emb, const float* __restrict__ item_emb,
    const float* __restrict__ relation_emb, const float* __restrict__ node_type_emb,
    float* __restrict__ ws)
{
  const int gid = blockIdx.x*256 + threadIdx.x;
  const int row = gid >> 3, seg = gid & 7;
  if (row >= 150010) return;
  const float* src; int dstoff;
  if (row < 100000){ src = user_emb + row*64;             dstoff = OFF_TU + row*32; }
  else if (row < 150000){ src = item_emb + (row-100000)*64; dstoff = OFF_TI + (row-100000)*32; }
  else if (row < 150008){ src = relation_emb + (row-150000)*64; dstoff = OFF_TR + (row-150000)*32; }
  else { src = node_type_emb + (row-150008)*64;           dstoff = OFF_TT + (row-150008)*32; }
  float4 v0 = ((const float4*)(src + seg*8))[0];
  float4 v1 = ((const float4*)(src + seg*8))[1];
  uint4 hq;
  hq.x = (unsigned)cvh(v0.x) | ((unsigned)cvh(v0.y)<<16);
  hq.y = (unsigned)cvh(v0.z) | ((unsigned)cvh(v0.w)<<16);
  hq.z = (unsigned)cvh(v1.x) | ((unsigned)cvh(v1.y)<<16);
  hq.w = (unsigned)cvh(v1.z) | ((unsigned)cvh(v1.w)<<16);
  *(uint4*)((char*)(ws + dstoff) + seg*16) = hq;
}

// ---------------------------------------------------------------- main: LSTM + attention (BM=32)
template<int PRE>
__global__ __launch_bounds__(512,4) void klstm(
    const int* __restrict__ node_ids, const int* __restrict__ node_types,
    const int* __restrict__ rel_idx,
    const float* __restrict__ user_emb, const float* __restrict__ item_emb,
    const float* __restrict__ relation_emb, const float* __restrict__ node_type_emb,
    const float* __restrict__ att_W2, const float* __restrict__ att_b2,
    float* __restrict__ ws)
{
  __shared__ __align__(16) unsigned char smem[LDS_BYTES];
  const int t   = threadIdx.x;
  const int l   = t & 63, wid = t >> 6;
  const int ln  = l & 15, lk = l >> 4;
  const int bid = blockIdx.x, p0 = bid*BM;
  const bf16x8* Bih = (const bf16x8*)(ws + OFF_BIH);
  const bf16x8* Bhh = (const bf16x8*)(ws + OFF_BHH);
  const bf16x8* Bab = (const bf16x8*)(ws + OFF_BA);
  const int swA = (ln&7)<<4;

  // ---- gather feats (4 steps x 3 srcs x 32 paths, hi only): 6 tasks/thread
  {
    const int c8 = t&7, rr = t>>3;
    #pragma unroll
    for (int i=0;i<6;++i){
      int task = rr + i*64;                 // [0,384)
      int src = task>>7, s = (task>>5)&3, p = task&31;
      int gi = (p0+p)*4 + s;
      int dsta = (s*32 + p)*384 + ((src*128 + c8*16) ^ ((p&7)<<4));
      if (PRE){
        const char* rp;
        if (src==0){ int nid = node_ids[gi];
                     rp = (const char*)(ws + (node_types[gi]==0 ? OFF_TU + nid*32 : OFF_TI + nid*32)); }
        else if (src==1){ rp = (const char*)(ws + OFF_TT + node_types[gi]*32); }
        else { rp = (const char*)(ws + OFF_TR + rel_idx[gi]*32); }
        *(uint4*)(smem + dsta) = *(const uint4*)(rp + c8*16);
      } else {
        const float* sp;
        if (src==0){ int nid = node_ids[gi]; sp = (node_types[gi]==0 ? user_emb : item_emb) + nid*64; }
        else if (src==1){ sp = node_type_emb + node_types[gi]*64; }
        else { sp = relation_emb + rel_idx[gi]*64; }
        float4 v0 = ((const float4*)sp)[c8*2];
        float4 v1 = ((const float4*)sp)[c8*2+1];
        uint4 hq;
        hq.x = (unsigned)cvh(v0.x) | ((unsigned)cvh(v0.y)<<16);
        hq.y = (unsigned)cvh(v0.z) | ((unsigned)cvh(v0.w)<<16);
        hq.z = (unsigned)cvh(v1.x) | ((unsigned)cvh(v1.y)<<16);
        hq.w = (unsigned)cvh(v1.z) | ((unsigned)cvh(v1.w)<<16);
        *(uint4*)(smem + dsta) = hq;
      }
    }
  }
  // ---- acc init with bias (permuted cols)
  f32x4 acc[4][2][2];     // [step][ptile][nt]
  {
    float bv0 = ws[OFF_BSUM + ((ln>>3))*64   + wid*8 + (ln&7)];
    float bv1 = ws[OFF_BSUM + (2+(ln>>3))*64 + wid*8 + (ln&7)];
    #pragma unroll
    for (int s=0;s<4;++s)
      #pragma unroll
      for (int pt=0;pt<2;++pt){
        acc[s][pt][0] = (f32x4){bv0,bv0,bv0,bv0};
        acc[s][pt][1] = (f32x4){bv1,bv1,bv1,bv1};
      }
  }
  __syncthreads();

  // ---- phase 1: Zfeat all 4 steps x 2 ptiles (K=192)
  #pragma unroll 2
  for (int kc=0;kc<6;++kc){
    bf16x8 bh0 = Bih[(unsigned)((kc*16 + wid*2+0)*64 + l)];
    bf16x8 bh1 = Bih[(unsigned)((kc*16 + wid*2+1)*64 + l)];
    #pragma unroll
    for (int s=0;s<4;++s)
      #pragma unroll
      for (int pt=0;pt<2;++pt){
        bf16x8 ah = *(const bf16x8*)(smem + (s*32 + pt*16 + ln)*384 + ((kc*64 + lk*16) ^ swA));
        acc[s][pt][0] = MFMA16(ah, bh0, acc[s][pt][0]);
        acc[s][pt][1] = MFMA16(ah, bh1, acc[s][pt][1]);
      }
  }

  // ---- phase 2: recurrence, gates from registers (shfl_xor 8)
  const int hi8 = ln>>3;
  const int dd  = wid*8 + (ln&7);
  float c0[2] = {0.f,0.f}, c1[2] = {0.f,0.f};
  #pragma unroll
  for (int s=0;s<4;++s){
    if (s > 0){
      const int rb = AHB + (s&1)*4096;
      #pragma unroll
      for (int kc=0;kc<2;++kc){
        bf16x8 bh0 = Bhh[(unsigned)((kc*16 + wid*2+0)*64 + l)];
        bf16x8 bh1 = Bhh[(unsigned)((kc*16 + wid*2+1)*64 + l)];
        #pragma unroll
        for (int pt=0;pt<2;++pt){
          bf16x8 ah = *(const bf16x8*)(smem + rb + (pt*16 + ln)*128 + ((kc*64 + lk*16) ^ swA));
          acc[s][pt][0] = MFMA16(ah, bh0, acc[s][pt][0]);
          acc[s][pt][1] = MFMA16(ah, bh1, acc[s][pt][1]);
        }
      }
    }
    const int wb = AHB + ((s&1)^1)*4096;
    #pragma unroll
    for (int pt=0;pt<2;++pt){
      float a00 = acc[s][pt][0][0], a01 = acc[s][pt][0][1], a02 = acc[s][pt][0][2], a03 = acc[s][pt][0][3];
      float a10 = acc[s][pt][1][0], a11 = acc[s][pt][1][1], a12 = acc[s][pt][1][2], a13 = acc[s][pt][1][3];
      float p00 = __shfl_xor(a00,8), p01 = __shfl_xor(a01,8);
      float p02 = __shfl_xor(a02,8), p03 = __shfl_xor(a03,8);
      float p10 = __shfl_xor(a10,8), p11 = __shfl_xor(a11,8);
      float p12 = __shfl_xor(a12,8), p13 = __shfl_xor(a13,8);
      float vi0 = hi8 ? p02 : a00;  float vf0 = hi8 ? a02 : p00;
      float vg0 = hi8 ? p12 : a10;  float vo0 = hi8 ? a12 : p10;
      float vi1 = hi8 ? p03 : a01;  float vf1 = hi8 ? a03 : p01;
      float vg1 = hi8 ? p13 : a11;  float vo1 = hi8 ? a13 : p11;
      float i0 = sigm_f(vi0), f0 = sigm_f(vf0), g0 = tanh_f(vg0), o0 = sigm_f(vo0);
      float i1 = sigm_f(vi1), f1 = sigm_f(vf1), g1 = tanh_f(vg1), o1 = sigm_f(vo1);
      c0[pt] = fmaf(f0, c0[pt], i0*g0);
      c1[pt] = fmaf(f1, c1[pt], i1*g1);
      float h0 = o0 * tanh_f(c0[pt]);
      float h1 = o1 * tanh_f(c1[pt]);
      int pth0 = pt*16 + lk*4 + hi8*2, pth1 = pth0 + 1;
      *(unsigned short*)(smem + wb + pth0*128 + ((dd*2) ^ ((pth0&7)<<4))) = cvh(h0);
      *(unsigned short*)(smem + wb + pth1*128 + ((dd*2) ^ ((pth1&7)<<4))) = cvh(h1);
    }
    __syncthreads();
  }
  // h_n now in AHB buf0 (bf16, swizzled)

  // ---- attention hidden: relu(h @ BA + ctxp) -> HIDB [32p][128] f32 overlays AF@0
  {
    const int pt = wid>>2, wg = wid&3;
    f32x4 acc2[2];
    #pragma unroll
    for (int nt=0;nt<2;++nt){
      float cv = ws[OFF_CTXP + wg*32 + nt*16 + ln];
      acc2[nt] = (f32x4){cv,cv,cv,cv};
    }
    #pragma unroll
    for (int kc=0;kc<2;++kc){
      bf16x8 ah = *(const bf16x8*)(smem + AHB + (pt*16 + ln)*128 + ((kc*64 + lk*16) ^ swA));
      bf16x8 bh0 = Bab[(unsigned)((kc*8 + wg*2+0)*64 + l)];
      bf16x8 bh1 = Bab[(unsigned)((kc*8 + wg*2+1)*64 + l)];
      acc2[0] = MFMA16(ah, bh0, acc2[0]);
      acc2[1] = MFMA16(ah, bh1, acc2[1]);
    }
    __syncthreads();   // AF reads done (phase1 done long ago); safe to overlay
    #pragma unroll
    for (int nt=0;nt<2;++nt)
      #pragma unroll
      for (int r=0;r<4;++r)
        *(float*)(smem + (pt*16 + lk*4+r)*512 + (wg*32 + nt*16 + ln)*4) = fmaxf(acc2[nt][r], 0.f);
  }
  __syncthreads();
  // ---- score = hidden . att_W2 + b2 ; e = exp(score)
  {
    int p = t>>4, seg = t&15;
    float4 a0 = *(const float4*)(smem + p*512 + seg*32);
    float4 a1 = *(const float4*)(smem + p*512 + seg*32 + 16);
    float4 w0 = *(const float4*)(att_W2 + seg*8);
    float4 w1 = *(const float4*)(att_W2 + seg*8 + 4);
    float sc = a0.x*w0.x; sc = fmaf(a0.y,w0.y,sc); sc = fmaf(a0.z,w0.z,sc); sc = fmaf(a0.w,w0.w,sc);
    sc = fmaf(a1.x,w1.x,sc); sc = fmaf(a1.y,w1.y,sc); sc = fmaf(a1.z,w1.z,sc); sc = fmaf(a1.w,w1.w,sc);
    sc += __shfl_xor(sc,1); sc += __shfl_xor(sc,2); sc += __shfl_xor(sc,4); sc += __shfl_xor(sc,8);
    if (seg == 0){
      float e = __expf(sc + att_b2[0]);
      *(float*)(smem + ESO + p*4) = e;
      ws[OFF_E + p0 + p] = e;
    }
  }
  __syncthreads();
  // ---- partial sums: sum(e), sum(e*h)  (h as bf16 from AHB buf0)
  {
    int pg = t>>6, d = t&63;
    const float* es = (const float*)(smem + ESO);
    float a = 0.f;
    #pragma unroll
    for (int pi=0;pi<4;++pi){
      int p = pg*4 + pi;
      unsigned short hu = *(const unsigned short*)(smem + AHB + p*128 + ((d*2) ^ ((p&7)<<4)));
      a = fmaf(es[p], __uint_as_float((unsigned)hu << 16), a);
    }
    *(float*)(smem + PARTO + (pg*64+d)*4) = a;
  }
  __syncthreads();
  if (t < 64){
    const float* part = (const float*)(smem + PARTO);
    float a = 0.f;
    #pragma unroll
    for (int pg=0;pg<8;++pg) a += part[pg*64 + t];
    ws[OFF_PAGG + bid*64 + t] = a;
  }
  if (t < 32){
    float e2 = *(const float*)(smem + ESO + t*4);
    e2 += __shfl_xor(e2,1); e2 += __shfl_xor(e2,2);
    e2 += __shfl_xor(e2,4); e2 += __shfl_xor(e2,8); e2 += __shfl_xor(e2,16);
    if (t==0) ws[OFF_PE + bid] = e2;
  }
}

// ---------------------------------------------------------------- reduce stage A: 64 blocks
__global__ __launch_bounds__(256) void kredA(float* __restrict__ ws)
{
  const float* p_e   = ws + OFF_PE;
  const float* p_agg = ws + OFF_PAGG;
  __shared__ float red[256];
  const int b = blockIdx.x, t = threadIdx.x;
  const int s = b*4 + (t>>6), d = t&63;
  float a = 0.f;
  for (int row = s; row < NBLK; row += 256) a += p_agg[row*64 + d];
  ws[OFF_P2AGG + s*64 + d] = a;
  float pe = 0.f;
  {
    int i = b*49 + t;
    if (t < 49 && i < NBLK) pe = p_e[i];
  }
  pe += __shfl_xor(pe,1); pe += __shfl_xor(pe,2); pe += __shfl_xor(pe,4);
  pe += __shfl_xor(pe,8); pe += __shfl_xor(pe,16); pe += __shfl_xor(pe,32);
  if ((t&63)==0) red[t>>6] = pe;
  __syncthreads();
  if (t==0) ws[OFF_P2E + b] = red[0]+red[1]+red[2]+red[3];
}

// ---------------------------------------------------------------- reduce stage B + heads: 1 block
__global__ __launch_bounds__(256) void kredB(
    const float* __restrict__ val_W1, const float* __restrict__ val_b1,
    const float* __restrict__ val_W2, const float* __restrict__ val_b2,
    float* __restrict__ ws, float* __restrict__ d_out)
{
  __shared__ float aggL[64];
  __shared__ float red[256];
  __shared__ float Zs;
  const int t = threadIdx.x;
  {
    float pe = (t < 64) ? ws[OFF_P2E + t] : 0.f;
    pe += __shfl_xor(pe,1); pe += __shfl_xor(pe,2); pe += __shfl_xor(pe,4);
    pe += __shfl_xor(pe,8); pe += __shfl_xor(pe,16); pe += __shfl_xor(pe,32);
    if (t==0){ Zs = pe; ws[OFF_MISC+1] = 1.f/pe; }
  }
  {
    int d = t&63, q = t>>6;
    float a = 0.f;
    #pragma unroll 4
    for (int s2=q; s2<256; s2+=4) a += ws[OFF_P2AGG + s2*64 + d];
    red[t] = a;
  }
  __syncthreads();
  if (t < 64) aggL[t] = (red[t] + red[64+t] + red[128+t] + red[192+t]) / Zs;
  __syncthreads();
  if (t < 32){
    float hv = val_b1[t];
    for (int k=0;k<64;++k) hv = fmaf(aggL[k], val_W1[t*64+k], hv);
    hv = fmaxf(hv, 0.f);
    float v = hv * val_W2[t];
    v += __shfl_xor(v,1); v += __shfl_xor(v,2); v += __shfl_xor(v,4);
    v += __shfl_xor(v,8); v += __shfl_xor(v,16);
    // q_value = value + (advantage - mean(advantage)) == value (advantage is [1])
    if (t==0) d_out[0] = (v + val_b2[0]) * ws[OFF_MISC+0];
  }
}

// ---------------------------------------------------------------- att weights out
__global__ __launch_bounds__(256) void kweights(
    const float* __restrict__ ws, float* __restrict__ d_out)
{
  int p = blockIdx.x*256 + threadIdx.x;
  if (p < P_TOT) d_out[1+p] = ws[OFF_E + p] * ws[OFF_MISC+1];
}

// ---------------------------------------------------------------- launch
extern "C" void kernel_launch(void* const* d_in, const int* in_sizes, int n_in,
                              void* d_out, int out_size, void* d_ws, size_t ws_size,
                              hipStream_t stream) {
  const int*   user_idx   = (const int*)  d_in[0];
  const int*   item_idx   = (const int*)  d_in[1];
  const int*   node_ids   = (const int*)  d_in[2];
  const int*   node_types = (const int*)  d_in[3];
  const int*   rel_idx    = (const int*)  d_in[4];
  const float* user_emb   = (const float*)d_in[5];
  const float* item_emb   = (const float*)d_in[6];
  const float* rel_emb    = (const float*)d_in[7];
  const float* ntype_emb  = (const float*)d_in[8];
  const float* W_ih       = (const float*)d_in[9];
  const float* W_hh       = (const float*)d_in[10];
  const float* b_ih       = (const float*)d_in[11];
  const float* b_hh       = (const float*)d_in[12];
  const float* att_W1     = (const float*)d_in[13];
  const float* att_b1     = (const float*)d_in[14];
  const float* att_W2     = (const float*)d_in[15];
  const float* att_b2     = (const float*)d_in[16];
  const float* val_W1     = (const float*)d_in[17];
  const float* val_b1     = (const float*)d_in[18];
  const float* val_W2     = (const float*)d_in[19];
  const float* val_b2     = (const float*)d_in[20];
  const float* saf_W1     = (const float*)d_in[25];
  const float* saf_b1     = (const float*)d_in[26];
  const float* saf_W2     = (const float*)d_in[27];
  const float* saf_b2     = (const float*)d_in[28];
  float* ws  = (float*)d_ws;
  float* out = (float*)d_out;

  const bool fast = (ws_size >= WS_FAST_BYTES);

  hipLaunchKernelGGL(kprep, dim3(64), dim3(256), 0, stream,
                     user_idx, item_idx, user_emb, item_emb,
                     W_ih, W_hh, b_ih, b_hh, att_W1, att_b1,
                     saf_W1, saf_b1, saf_W2, saf_b2, ws);
  if (fast){
    hipLaunchKernelGGL(kconv, dim3((150010*8+255)/256), dim3(256), 0, stream,
                       user_emb, item_emb, rel_emb, ntype_emb, ws);
    hipLaunchKernelGGL(klstm<1>, dim3(NBLK), dim3(512), 0, stream,
                       node_ids, node_types, rel_idx,
                       user_emb, item_emb, rel_emb, ntype_emb,
                       att_W2, att_b2, ws);
  } else {
    hipLaunchKernelGGL(klstm<0>, dim3(NBLK), dim3(512), 0, stream,
                       node_ids, node_types, rel_idx,
                       user_emb, item_emb, rel_emb, ntype_emb,
                       att_W2, att_b2, ws);
  }
  hipLaunchKernelGGL(kredA, dim3(64), dim3(256), 0, stream, ws);
  hipLaunchKernelGGL(kredB, dim3(1), dim3(256), 0, stream,
                     val_W1, val_b1, val_W2, val_b2, ws, out);
  hipLaunchKernelGGL(kweights, dim3((P_TOT+255)/256), dim3(256), 0, stream,
                     ws, out);
}

// Round 11
// 118.745 us; speedup vs baseline: 2.7757x; 1.2136x over previous
//
#include <hip/hip_runtime.h>
#include <math.h>

#define P_TOT 100000
#define BM    32
#define NBLK  3125

// ws float offsets
#define OFF_BIH   0        // 96 frags (6kc x 8w x 2nt) x 1KB, GATE-PERMUTED cols, hi only, exp2-prescaled
#define OFF_BHH   24576    // 32 frags (2kc x 8w x 2nt), gate-permuted, hi only, exp2-prescaled
#define OFF_BA    32768    // 16 frags (2kc x 8ntg), standard cols, hi only (NOT scaled)
#define OFF_BSUM  36864    // 256 (natural order, exp2-prescaled)
#define OFF_CTXP  37120    // 128
#define OFF_MISC  37248    // [0]=safety, [1]=invZ
#define OFF_E     37264    // 100000
#define OFF_PE    137264   // 3125
#define OFF_PAGG  140392   // 3125*64
#define OFF_P2E   340392   // 64
#define OFF_P2AGG 340456   // 256*64
// hi-only bf16 embedding tables: [row][128B] = 32 f32-slots/row
#define OFF_TAB   356864
#define OFF_TU    (OFF_TAB)                 // 100000 rows
#define OFF_TI    (OFF_TAB + 3200000)       // 50000 rows
#define OFF_TR    (OFF_TAB + 4800000)       // 8 rows
#define OFF_TT    (OFF_TAB + 4800256)       // 2 rows
#define WS_FAST_BYTES ((size_t)(OFF_TAB + 4800320) * 4)

// klstm LDS (59520 B) — same as r10
#define AHB   49152
#define ESO   57344
#define PARTO 57472
#define LDS_BYTES 59520

#define LOG2E  1.442695041f
#define LOG2E2 2.885390082f

typedef short bf16x8 __attribute__((ext_vector_type(8)));
typedef float f32x4  __attribute__((ext_vector_type(4)));

#define MFMA16(a,b,c) __builtin_amdgcn_mfma_f32_16x16x32_bf16((a),(b),(c),0,0,0)

__device__ __forceinline__ unsigned short cvh(float v){
  unsigned int u = __float_as_uint(v);
  return (unsigned short)((u + 0x7fffu + ((u>>16)&1u)) >> 16);
}
__device__ __forceinline__ float fexp2(float x){
#if __has_builtin(__builtin_amdgcn_exp2f)
  return __builtin_amdgcn_exp2f(x);
#else
  return exp2f(x);
#endif
}
__device__ __forceinline__ float frcp(float x){
#if __has_builtin(__builtin_amdgcn_rcpf)
  return __builtin_amdgcn_rcpf(x);
#else
  return 1.f/x;
#endif
}
// zp = z * log2e  (pre-scaled in weights)
__device__ __forceinline__ float sigm2(float zp){ return frcp(1.f + fexp2(-zp)); }
// zp = 2*z*log2e  (pre-scaled in weights for g gate)
__device__ __forceinline__ float tanh2(float zp){
  float e2 = fexp2(zp);
  return (e2 - 1.f) * frcp(e2 + 1.f);
}
__device__ __forceinline__ float tanh_c(float c){ return tanh2(c * LOG2E2); }
__device__ __forceinline__ float sigm_f(float x){ return 1.f/(1.f+__expf(-x)); }

// ---------------------------------------------------------------- prep (weights)
__global__ __launch_bounds__(256) void kprep(
    const int* __restrict__ user_idx, const int* __restrict__ item_idx,
    const float* __restrict__ user_emb, const float* __restrict__ item_emb,
    const float* __restrict__ W_ih, const float* __restrict__ W_hh,
    const float* __restrict__ b_ih, const float* __restrict__ b_hh,
    const float* __restrict__ att_W1, const float* __restrict__ att_b1,
    const float* __restrict__ saf_W1, const float* __restrict__ saf_b1,
    const float* __restrict__ saf_W2, const float* __restrict__ saf_b2,
    float* __restrict__ ws)
{
  const int t = threadIdx.x;
  for (int fb = blockIdx.x; fb < 144; fb += gridDim.x){
    const float* src; int base, rowlen, kc; bool perm; int w=0, nt=0, ntg=0;
    if (fb < 96){ kc = fb>>4; int rem = fb&15; w = rem>>1; nt = rem&1; perm = true;
                  base = OFF_BIH + fb*256; src = W_ih; rowlen = 192; }
    else if (fb < 128){ int f2 = fb-96; kc = f2>>4; int rem = f2&15; w = rem>>1; nt = rem&1; perm = true;
                  base = OFF_BHH + f2*256; src = W_hh; rowlen = 64; }
    else { int f3 = fb-128; kc = f3>>3; ntg = f3&7; perm = false;
                  base = OFF_BA + f3*256; src = att_W1; rowlen = 192; }
    unsigned short* dst = (unsigned short*)(ws + base);
    for (int e = t; e < 512; e += 256){
      int l = e>>3, j = e&7;
      int c = l&15;
      int n = perm ? (nt*2 + (c>>3))*64 + w*8 + (c&7)
                   : ntg*16 + c;
      int k = kc*32 + (l>>4)*8 + j;
      float v = src[n*rowlen + k];
      if (perm) v *= ((n>>6)==2 ? LOG2E2 : LOG2E);   // exp2 pre-scale per gate
      dst[e] = cvh(v);
    }
  }
  if (blockIdx.x == 0){
    __shared__ float ctx[128];
    if (t < 256) ws[OFF_BSUM+t] = (b_ih[t] + b_hh[t]) * ((t>>6)==2 ? LOG2E2 : LOG2E);
    if (t < 64){
      ctx[t]    = user_emb[user_idx[0]*64 + t];
      ctx[64+t] = item_emb[item_idx[0]*64 + t];
    }
    __syncthreads();
    if (t < 128){
      float s = att_b1[t];
      for (int k=0;k<128;++k) s = fmaf(att_W1[t*192 + 64 + k], ctx[k], s);
      ws[OFF_CTXP + t] = s;
    }
    if (t < 32){
      float s = saf_b1[t];
      for (int k=0;k<128;++k) s = fmaf(saf_W1[t*128+k], ctx[k], s);
      s = fmaxf(s, 0.f);
      float v = s * saf_W2[t];
      v += __shfl_xor(v,1); v += __shfl_xor(v,2); v += __shfl_xor(v,4);
      v += __shfl_xor(v,8); v += __shfl_xor(v,16);
      if (t==0) ws[OFF_MISC+0] = 1.f/(1.f+expf(-(v + saf_b2[0])));
    }
  }
}

// ---------------------------------------------------------------- table conversion (hi-only)
__global__ __launch_bounds__(256) void kconv(
    const float* __restrict__ user_emb, const float* __restrict__ item_emb,
    const float* __restrict__ relation_emb, const float* __restrict__ node_type_emb,
    float* __restrict__ ws)
{
  const int gid = blockIdx.x*256 + threadIdx.x;
  const int row = gid >> 3, seg = gid & 7;
  if (row >= 150010) return;
  const float* src; int dstoff;
  if (row < 100000){ src = user_emb + row*64;             dstoff = OFF_TU + row*32; }
  else if (row < 150000){ src = item_emb + (row-100000)*64; dstoff = OFF_TI + (row-100000)*32; }
  else if (row < 150008){ src = relation_emb + (row-150000)*64; dstoff = OFF_TR + (row-150000)*32; }
  else { src = node_type_emb + (row-150008)*64;           dstoff = OFF_TT + (row-150008)*32; }
  float4 v0 = ((const float4*)(src + seg*8))[0];
  float4 v1 = ((const float4*)(src + seg*8))[1];
  uint4 hq;
  hq.x = (unsigned)cvh(v0.x) | ((unsigned)cvh(v0.y)<<16);
  hq.y = (unsigned)cvh(v0.z) | ((unsigned)cvh(v0.w)<<16);
  hq.z = (unsigned)cvh(v1.x) | ((unsigned)cvh(v1.y)<<16);
  hq.w = (unsigned)cvh(v1.z) | ((unsigned)cvh(v1.w)<<16);
  *(uint4*)((char*)(ws + dstoff) + seg*16) = hq;
}

// ---------------------------------------------------------------- main: LSTM + attention (BM=32)
template<int PRE>
__global__ __launch_bounds__(512,4) void klstm(
    const int* __restrict__ node_ids, const int* __restrict__ node_types,
    const int* __restrict__ rel_idx,
    const float* __restrict__ user_emb, const float* __restrict__ item_emb,
    const float* __restrict__ relation_emb, const float* __restrict__ node_type_emb,
    const float* __restrict__ att_W2, const float* __restrict__ att_b2,
    float* __restrict__ ws)
{
  __shared__ __align__(16) unsigned char smem[LDS_BYTES];
  const int t   = threadIdx.x;
  const int l   = t & 63, wid = t >> 6;
  const int ln  = l & 15, lk = l >> 4;
  const int bid = blockIdx.x, p0 = bid*BM;
  const bf16x8* Bih = (const bf16x8*)(ws + OFF_BIH);
  const bf16x8* Bhh = (const bf16x8*)(ws + OFF_BHH);
  const bf16x8* Bab = (const bf16x8*)(ws + OFF_BA);
  const int swA = (ln&7)<<4;

  // ---- gather feats (4 steps x 3 srcs x 32 paths, hi only): 6 tasks/thread
  {
    const int c8 = t&7, rr = t>>3;
    #pragma unroll
    for (int i=0;i<6;++i){
      int task = rr + i*64;                 // [0,384)
      int src = task>>7, s = (task>>5)&3, p = task&31;
      int gi = (p0+p)*4 + s;
      int dsta = (s*32 + p)*384 + ((src*128 + c8*16) ^ ((p&7)<<4));
      if (PRE){
        const char* rp;
        if (src==0){ int nid = node_ids[gi];
                     rp = (const char*)(ws + (node_types[gi]==0 ? OFF_TU + nid*32 : OFF_TI + nid*32)); }
        else if (src==1){ rp = (const char*)(ws + OFF_TT + node_types[gi]*32); }
        else { rp = (const char*)(ws + OFF_TR + rel_idx[gi]*32); }
        *(uint4*)(smem + dsta) = *(const uint4*)(rp + c8*16);
      } else {
        const float* sp;
        if (src==0){ int nid = node_ids[gi]; sp = (node_types[gi]==0 ? user_emb : item_emb) + nid*64; }
        else if (src==1){ sp = node_type_emb + node_types[gi]*64; }
        else { sp = relation_emb + rel_idx[gi]*64; }
        float4 v0 = ((const float4*)sp)[c8*2];
        float4 v1 = ((const float4*)sp)[c8*2+1];
        uint4 hq;
        hq.x = (unsigned)cvh(v0.x) | ((unsigned)cvh(v0.y)<<16);
        hq.y = (unsigned)cvh(v0.z) | ((unsigned)cvh(v0.w)<<16);
        hq.z = (unsigned)cvh(v1.x) | ((unsigned)cvh(v1.y)<<16);
        hq.w = (unsigned)cvh(v1.z) | ((unsigned)cvh(v1.w)<<16);
        *(uint4*)(smem + dsta) = hq;
      }
    }
  }
  // ---- acc init with bias (permuted cols)
  f32x4 acc[4][2][2];     // [step][ptile][nt]
  {
    float bv0 = ws[OFF_BSUM + ((ln>>3))*64   + wid*8 + (ln&7)];
    float bv1 = ws[OFF_BSUM + (2+(ln>>3))*64 + wid*8 + (ln&7)];
    #pragma unroll
    for (int s=0;s<4;++s)
      #pragma unroll
      for (int pt=0;pt<2;++pt){
        acc[s][pt][0] = (f32x4){bv0,bv0,bv0,bv0};
        acc[s][pt][1] = (f32x4){bv1,bv1,bv1,bv1};
      }
  }
  __syncthreads();

  // ---- phase 1: Zfeat all 4 steps x 2 ptiles (K=192)
  #pragma unroll 2
  for (int kc=0;kc<6;++kc){
    bf16x8 bh0 = Bih[(unsigned)((kc*16 + wid*2+0)*64 + l)];
    bf16x8 bh1 = Bih[(unsigned)((kc*16 + wid*2+1)*64 + l)];
    #pragma unroll
    for (int s=0;s<4;++s)
      #pragma unroll
      for (int pt=0;pt<2;++pt){
        bf16x8 ah = *(const bf16x8*)(smem + (s*32 + pt*16 + ln)*384 + ((kc*64 + lk*16) ^ swA));
        acc[s][pt][0] = MFMA16(ah, bh0, acc[s][pt][0]);
        acc[s][pt][1] = MFMA16(ah, bh1, acc[s][pt][1]);
      }
  }

  // ---- phase 2: recurrence, gates from registers (shfl_xor 8)
  const int hi8 = ln>>3;
  const int dd  = wid*8 + (ln&7);
  float c0[2] = {0.f,0.f}, c1[2] = {0.f,0.f};
  #pragma unroll
  for (int s=0;s<4;++s){
    if (s > 0){
      const int rb = AHB + (s&1)*4096;
      #pragma unroll
      for (int kc=0;kc<2;++kc){
        bf16x8 bh0 = Bhh[(unsigned)((kc*16 + wid*2+0)*64 + l)];
        bf16x8 bh1 = Bhh[(unsigned)((kc*16 + wid*2+1)*64 + l)];
        #pragma unroll
        for (int pt=0;pt<2;++pt){
          bf16x8 ah = *(const bf16x8*)(smem + rb + (pt*16 + ln)*128 + ((kc*64 + lk*16) ^ swA));
          acc[s][pt][0] = MFMA16(ah, bh0, acc[s][pt][0]);
          acc[s][pt][1] = MFMA16(ah, bh1, acc[s][pt][1]);
        }
      }
    }
    const int wb = AHB + ((s&1)^1)*4096;
    #pragma unroll
    for (int pt=0;pt<2;++pt){
      float a00 = acc[s][pt][0][0], a01 = acc[s][pt][0][1], a02 = acc[s][pt][0][2], a03 = acc[s][pt][0][3];
      float a10 = acc[s][pt][1][0], a11 = acc[s][pt][1][1], a12 = acc[s][pt][1][2], a13 = acc[s][pt][1][3];
      float p00 = __shfl_xor(a00,8), p01 = __shfl_xor(a01,8);
      float p02 = __shfl_xor(a02,8), p03 = __shfl_xor(a03,8);
      float p10 = __shfl_xor(a10,8), p11 = __shfl_xor(a11,8);
      float p12 = __shfl_xor(a12,8), p13 = __shfl_xor(a13,8);
      float vi0 = hi8 ? p02 : a00;  float vf0 = hi8 ? a02 : p00;
      float vg0 = hi8 ? p12 : a10;  float vo0 = hi8 ? a12 : p10;
      float vi1 = hi8 ? p03 : a01;  float vf1 = hi8 ? a03 : p01;
      float vg1 = hi8 ? p13 : a11;  float vo1 = hi8 ? a13 : p11;
      float i0 = sigm2(vi0), f0 = sigm2(vf0), g0 = tanh2(vg0), o0 = sigm2(vo0);
      float i1 = sigm2(vi1), f1 = sigm2(vf1), g1 = tanh2(vg1), o1 = sigm2(vo1);
      c0[pt] = fmaf(f0, c0[pt], i0*g0);
      c1[pt] = fmaf(f1, c1[pt], i1*g1);
      float h0 = o0 * tanh_c(c0[pt]);
      float h1 = o1 * tanh_c(c1[pt]);
      int pth0 = pt*16 + lk*4 + hi8*2, pth1 = pth0 + 1;
      *(unsigned short*)(smem + wb + pth0*128 + ((dd*2) ^ ((pth0&7)<<4))) = cvh(h0);
      *(unsigned short*)(smem + wb + pth1*128 + ((dd*2) ^ ((pth1&7)<<4))) = cvh(h1);
    }
    __syncthreads();
  }
  // h_n now in AHB buf0 (bf16, swizzled)

  // ---- attention hidden: relu(h @ BA + ctxp) -> HIDB [32p][128] f32 overlays AF@0
  {
    const int pt = wid>>2, wg = wid&3;
    f32x4 acc2[2];
    #pragma unroll
    for (int nt=0;nt<2;++nt){
      float cv = ws[OFF_CTXP + wg*32 + nt*16 + ln];
      acc2[nt] = (f32x4){cv,cv,cv,cv};
    }
    #pragma unroll
    for (int kc=0;kc<2;++kc){
      bf16x8 ah = *(const bf16x8*)(smem + AHB + (pt*16 + ln)*128 + ((kc*64 + lk*16) ^ swA));
      bf16x8 bh0 = Bab[(unsigned)((kc*8 + wg*2+0)*64 + l)];
      bf16x8 bh1 = Bab[(unsigned)((kc*8 + wg*2+1)*64 + l)];
      acc2[0] = MFMA16(ah, bh0, acc2[0]);
      acc2[1] = MFMA16(ah, bh1, acc2[1]);
    }
    __syncthreads();   // AF reads done; safe to overlay
    #pragma unroll
    for (int nt=0;nt<2;++nt)
      #pragma unroll
      for (int r=0;r<4;++r)
        *(float*)(smem + (pt*16 + lk*4+r)*512 + (wg*32 + nt*16 + ln)*4) = fmaxf(acc2[nt][r], 0.f);
  }
  __syncthreads();
  // ---- score = hidden . att_W2 + b2 ; e = exp(score)
  {
    int p = t>>4, seg = t&15;
    float4 a0 = *(const float4*)(smem + p*512 + seg*32);
    float4 a1 = *(const float4*)(smem + p*512 + seg*32 + 16);
    float4 w0 = *(const float4*)(att_W2 + seg*8);
    float4 w1 = *(const float4*)(att_W2 + seg*8 + 4);
    float sc = a0.x*w0.x; sc = fmaf(a0.y,w0.y,sc); sc = fmaf(a0.z,w0.z,sc); sc = fmaf(a0.w,w0.w,sc);
    sc = fmaf(a1.x,w1.x,sc); sc = fmaf(a1.y,w1.y,sc); sc = fmaf(a1.z,w1.z,sc); sc = fmaf(a1.w,w1.w,sc);
    sc += __shfl_xor(sc,1); sc += __shfl_xor(sc,2); sc += __shfl_xor(sc,4); sc += __shfl_xor(sc,8);
    if (seg == 0){
      float e = __expf(sc + att_b2[0]);
      *(float*)(smem + ESO + p*4) = e;
      ws[OFF_E + p0 + p] = e;
    }
  }
  __syncthreads();
  // ---- partial sums: sum(e), sum(e*h)  (h as bf16 from AHB buf0)
  {
    int pg = t>>6, d = t&63;
    const float* es = (const float*)(smem + ESO);
    float a = 0.f;
    #pragma unroll
    for (int pi=0;pi<4;++pi){
      int p = pg*4 + pi;
      unsigned short hu = *(const unsigned short*)(smem + AHB + p*128 + ((d*2) ^ ((p&7)<<4)));
      a = fmaf(es[p], __uint_as_float((unsigned)hu << 16), a);
    }
    *(float*)(smem + PARTO + (pg*64+d)*4) = a;
  }
  __syncthreads();
  if (t < 64){
    const float* part = (const float*)(smem + PARTO);
    float a = 0.f;
    #pragma unroll
    for (int pg=0;pg<8;++pg) a += part[pg*64 + t];
    ws[OFF_PAGG + bid*64 + t] = a;
  }
  if (t < 32){
    float e2 = *(const float*)(smem + ESO + t*4);
    e2 += __shfl_xor(e2,1); e2 += __shfl_xor(e2,2);
    e2 += __shfl_xor(e2,4); e2 += __shfl_xor(e2,8); e2 += __shfl_xor(e2,16);
    if (t==0) ws[OFF_PE + bid] = e2;
  }
}

// ---------------------------------------------------------------- reduce stage A: 64 blocks
__global__ __launch_bounds__(256) void kredA(float* __restrict__ ws)
{
  const float* p_e   = ws + OFF_PE;
  const float* p_agg = ws + OFF_PAGG;
  __shared__ float red[256];
  const int b = blockIdx.x, t = threadIdx.x;
  const int s = b*4 + (t>>6), d = t&63;
  float a = 0.f;
  for (int row = s; row < NBLK; row += 256) a += p_agg[row*64 + d];
  ws[OFF_P2AGG + s*64 + d] = a;
  float pe = 0.f;
  {
    int i = b*49 + t;
    if (t < 49 && i < NBLK) pe = p_e[i];
  }
  pe += __shfl_xor(pe,1); pe += __shfl_xor(pe,2); pe += __shfl_xor(pe,4);
  pe += __shfl_xor(pe,8); pe += __shfl_xor(pe,16); pe += __shfl_xor(pe,32);
  if ((t&63)==0) red[t>>6] = pe;
  __syncthreads();
  if (t==0) ws[OFF_P2E + b] = red[0]+red[1]+red[2]+red[3];
}

// ---------------------------------------------------------------- reduce stage B + heads: 1 block
__global__ __launch_bounds__(256) void kredB(
    const float* __restrict__ val_W1, const float* __restrict__ val_b1,
    const float* __restrict__ val_W2, const float* __restrict__ val_b2,
    float* __restrict__ ws, float* __restrict__ d_out)
{
  __shared__ float aggL[64];
  __shared__ float red[256];
  __shared__ float Zs;
  const int t = threadIdx.x;
  {
    float pe = (t < 64) ? ws[OFF_P2E + t] : 0.f;
    pe += __shfl_xor(pe,1); pe += __shfl_xor(pe,2); pe += __shfl_xor(pe,4);
    pe += __shfl_xor(pe,8); pe += __shfl_xor(pe,16); pe += __shfl_xor(pe,32);
    if (t==0){ Zs = pe; ws[OFF_MISC+1] = 1.f/pe; }
  }
  {
    int d = t&63, q = t>>6;
    float a = 0.f;
    #pragma unroll 4
    for (int s2=q; s2<256; s2+=4) a += ws[OFF_P2AGG + s2*64 + d];
    red[t] = a;
  }
  __syncthreads();
  if (t < 64) aggL[t] = (red[t] + red[64+t] + red[128+t] + red[192+t]) / Zs;
  __syncthreads();
  if (t < 32){
    float hv = val_b1[t];
    for (int k=0;k<64;++k) hv = fmaf(aggL[k], val_W1[t*64+k], hv);
    hv = fmaxf(hv, 0.f);
    float v = hv * val_W2[t];
    v += __shfl_xor(v,1); v += __shfl_xor(v,2); v += __shfl_xor(v,4);
    v += __shfl_xor(v,8); v += __shfl_xor(v,16);
    // q_value = value + (advantage - mean(advantage)) == value (advantage is [1])
    if (t==0) d_out[0] = (v + val_b2[0]) * ws[OFF_MISC+0];
  }
}

// ---------------------------------------------------------------- att weights out
__global__ __launch_bounds__(256) void kweights(
    const float* __restrict__ ws, float* __restrict__ d_out)
{
  int p = blockIdx.x*256 + threadIdx.x;
  if (p < P_TOT) d_out[1+p] = ws[OFF_E + p] * ws[OFF_MISC+1];
}

// ---------------------------------------------------------------- launch
extern "C" void kernel_launch(void* const* d_in, const int* in_sizes, int n_in,
                              void* d_out, int out_size, void* d_ws, size_t ws_size,
                              hipStream_t stream) {
  const int*   user_idx   = (const int*)  d_in[0];
  const int*   item_idx   = (const int*)  d_in[1];
  const int*   node_ids   = (const int*)  d_in[2];
  const int*   node_types = (const int*)  d_in[3];
  const int*   rel_idx    = (const int*)  d_in[4];
  const float* user_emb   = (const float*)d_in[5];
  const float* item_emb   = (const float*)d_in[6];
  const float* rel_emb    = (const float*)d_in[7];
  const float* ntype_emb  = (const float*)d_in[8];
  const float* W_ih       = (const float*)d_in[9];
  const float* W_hh       = (const float*)d_in[10];
  const float* b_ih       = (const float*)d_in[11];
  const float* b_hh       = (const float*)d_in[12];
  const float* att_W1     = (const float*)d_in[13];
  const float* att_b1     = (const float*)d_in[14];
  const float* att_W2     = (const float*)d_in[15];
  const float* att_b2     = (const float*)d_in[16];
  const float* val_W1     = (const float*)d_in[17];
  const float* val_b1     = (const float*)d_in[18];
  const float* val_W2     = (const float*)d_in[19];
  const float* val_b2     = (const float*)d_in[20];
  const float* saf_W1     = (const float*)d_in[25];
  const float* saf_b1     = (const float*)d_in[26];
  const float* saf_W2     = (const float*)d_in[27];
  const float* saf_b2     = (const float*)d_in[28];
  float* ws  = (float*)d_ws;
  float* out = (float*)d_out;

  const bool fast = (ws_size >= WS_FAST_BYTES);

  hipLaunchKernelGGL(kprep, dim3(64), dim3(256), 0, stream,
                     user_idx, item_idx, user_emb, item_emb,
                     W_ih, W_hh, b_ih, b_hh, att_W1, att_b1,
                     saf_W1, saf_b1, saf_W2, saf_b2, ws);
  if (fast){
    hipLaunchKernelGGL(kconv, dim3((150010*8+255)/256), dim3(256), 0, stream,
                       user_emb, item_emb, rel_emb, ntype_emb, ws);
    hipLaunchKernelGGL(klstm<1>, dim3(NBLK), dim3(512), 0, stream,
                       node_ids, node_types, rel_idx,
                       user_emb, item_emb, rel_emb, ntype_emb,
                       att_W2, att_b2, ws);
  } else {
    hipLaunchKernelGGL(klstm<0>, dim3(NBLK), dim3(512), 0, stream,
                       node_ids, node_types, rel_idx,
                       user_emb, item_emb, rel_emb, ntype_emb,
                       att_W2, att_b2, ws);
  }
  hipLaunchKernelGGL(kredA, dim3(64), dim3(256), 0, stream, ws);
  hipLaunchKernelGGL(kredB, dim3(1), dim3(256), 0, stream,
                     val_W1, val_b1, val_W2, val_b2, ws, out);
  hipLaunchKernelGGL(kweights, dim3((P_TOT+255)/256), dim3(256), 0, stream,
                     ws, out);
}